// Round 12
// baseline (290.084 us; speedup 1.0000x reference)
//
#include <hip/hip_runtime.h>
#include <hip/hip_bf16.h>
#include <math.h>

#define NPTS  8192
#define DIM   512
#define KNNK  15
#define NCAND 22
#define NPAIR 105
#define CINF  3.0e38f
#define EMPTYK 0xFFFFFFFFu
#define TAU_MARGIN (3u << 16)   // +3 bf16 ulp on the screen threshold

// knn tiling
#define NI      128
#define NJSPLIT 16
#define NJ      (NPTS/NJSPLIT)   // 512
#define JS      128
#define NSUB    (NJ/JS)          // 4
#define BK      32
#define NCH     (DIM/BK)         // 16 chunks, double-buffered
#define SDW     68               // packed sdist row stride in dwords
#define NPROBE  16               // probe subtiles (j < 2048 = splits 0..3)
#define NMAIN   (NJSPLIT - 4)    // 12 main splits
#define NLIST   (NPROBE + NMAIN) // 28 lists per point
#define NKEYS   (NLIST * KNNK)   // 420 keys per point
#define NPKEYS  (NPROBE * KNNK)  // 240 probe keys

// knn LDS byte map (39936 B -> 4 blocks/CU)
#define BUF0_OFF   0
#define BUF1_OFF   16384
#define SQJ_OFF    34816
#define KNN_LDS    39936

typedef __attribute__((ext_vector_type(8))) short short8;
typedef __attribute__((ext_vector_type(4))) float f32x4;
typedef unsigned int uint32;

static __device__ __forceinline__ float wave_sum_f(float v) {
#pragma unroll
  for (int m = 32; m > 0; m >>= 1) v += __shfl_xor(v, m, 64);
  return v;
}

static __device__ __forceinline__ void load_lds16(const void* g, void* l) {
  __builtin_amdgcn_global_load_lds(
      (const __attribute__((address_space(1))) void*)g,
      (__attribute__((address_space(3))) void*)l, 16, 0, 0);
}

static __device__ __forceinline__ void bf16split(float x, short& h, short& l) {
  __hip_bfloat16 hb = __float2bfloat16(x);
  const float hf = __bfloat162float(hb);
  __hip_bfloat16 lb = __float2bfloat16(x - hf);
  h = *(short*)&hb;
  l = *(short*)&lb;
}

// # of set bits of B strictly below this lane
static __device__ __forceinline__ int lanes_below(unsigned long long B) {
  int c = __builtin_amdgcn_mbcnt_lo((uint32)B, 0);
  return __builtin_amdgcn_mbcnt_hi((uint32)(B >> 32), c);
}

// sorted-ascending insert of key c into td[0..14]
static __device__ __forceinline__ void chain15(uint32 (&td)[15], uint32 c) {
#pragma unroll
  for (int p = 0; p < 15; ++p) {
    const uint32 lo = min(c, td[p]);
    const uint32 hi = max(c, td[p]);
    td[p] = lo; c = hi;
  }
}

#define PUSHK(k_) { const uint32 kv_ = (k_); \
  p0=(nc==0)?kv_:p0;  p1=(nc==1)?kv_:p1;  p2=(nc==2)?kv_:p2; \
  p3=(nc==3)?kv_:p3;  p4=(nc==4)?kv_:p4;  p5=(nc==5)?kv_:p5; \
  p6=(nc==6)?kv_:p6;  p7=(nc==7)?kv_:p7;  p8=(nc==8)?kv_:p8; \
  p9=(nc==9)?kv_:p9;  p10=(nc==10)?kv_:p10; p11=(nc==11)?kv_:p11; \
  ++nc; }

#define DRAINALL { \
  if (__any(nc >  0)) { if (nc >  0) chain15(td, p0);  } \
  if (__any(nc >  1)) { if (nc >  1) chain15(td, p1);  } \
  if (__any(nc >  2)) { if (nc >  2) chain15(td, p2);  } \
  if (__any(nc >  3)) { if (nc >  3) chain15(td, p3);  } \
  if (__any(nc >  4)) { if (nc >  4) chain15(td, p4);  } \
  if (__any(nc >  5)) { if (nc >  5) chain15(td, p5);  } \
  if (__any(nc >  6)) { if (nc >  6) chain15(td, p6);  } \
  if (__any(nc >  7)) { if (nc >  7) chain15(td, p7);  } \
  if (__any(nc >  8)) { if (nc >  8) chain15(td, p8);  } \
  if (__any(nc >  9)) { if (nc >  9) chain15(td, p9);  } \
  if (__any(nc > 10)) { if (nc > 10) chain15(td, p10); } \
  if (__any(nc > 11)) { if (nc > 11) chain15(td, p11); } \
  nc = 0; guard = min(tau_cur, td[14]); }

// ---------------------------------------------------------------- prep
__global__ __launch_bounds__(256) void prep_kernel(
    const float* __restrict__ E, float* __restrict__ sqn,
    ushort* __restrict__ EA, ushort* __restrict__ EB) {
  const int row  = blockIdx.x * 4 + (threadIdx.x >> 6);
  const int lane = threadIdx.x & 63;
  const float SR2 = 1.4142135623730951f;
  float s = 0.f;
#pragma unroll
  for (int c = 0; c < 8; ++c) {
    const int d0 = lane + 64 * c;
    const float x = E[(size_t)row * DIM + d0];
    s = fmaf(x, x, s);
    __hip_bfloat16 ha = __float2bfloat16(-SR2 * x);
    __hip_bfloat16 hb = __float2bfloat16( SR2 * x);
    EA[(size_t)row * DIM + d0] = *(ushort*)&ha;
    EB[(size_t)row * DIM + d0] = *(ushort*)&hb;
  }
  s = wave_sum_f(s);
  if (lane == 0) sqn[row] = s;
}

// ---------------------------------------------------------------- probe
// One 128x128 subtile of j<2048 per block (grid 64x16 = 1024 = 4/CU,
// same occupancy as main). Writes per-row sorted top-15 key list.
__global__ __launch_bounds__(256, 4) void knn_probe(
    const ushort* __restrict__ EA, const ushort* __restrict__ EB,
    const float* __restrict__ sqn, uint32* __restrict__ knnk) {
  __shared__ __align__(16) char sm[KNN_LDS];
  uint32* sdp  = (uint32*)sm;
  float*  sqjs = (float*)(sm + SQJ_OFF);

  const int tid = threadIdx.x;
  const int w   = tid >> 6;
  const int L   = tid & 63;
  const int wr  = (w >> 1) & 1;
  const int wc  = w & 1;
  const int i0  = blockIdx.x * NI;
  const int j0p = blockIdx.y * JS;     // 0..1920

  if (tid < 32) ((float4*)sqjs)[tid] = ((const float4*)(sqn + j0p))[tid];

  const ushort* gsrc = (w < 2) ? EA : EB;
  const int lrow  = L >> 2;
  const int swz_k = ((L & 3) ^ ((L >> 3) & 3)) * 8;
  const int lds_woff = ((w < 2) ? 0 : 8192) + (w & 1) * 4096;
  const int slot8 = (((L >> 4) ^ ((L >> 1) & 3)) * 8);

  const int myrow = tid >> 1;
  const int h     = tid & 1;
  const int gi    = i0 + myrow;

  uint32 td[15];
#pragma unroll
  for (int p = 0; p < 15; ++p) td[p] = EMPTYK;

  const int trowW = ((w < 2) ? i0 : j0p) + (w & 1) * 64;
  const ushort* gbase = gsrc + (size_t)(trowW + lrow) * DIM + swz_k;

  f32x4 acc[4][4];
  __syncthreads();
#pragma unroll
  for (int fj = 0; fj < 4; ++fj) {
    const f32x4 sq = *(const f32x4*)&sqjs[wc * 64 + fj * 16 + (L >> 4) * 4];
#pragma unroll
    for (int fi = 0; fi < 4; ++fi) acc[fj][fi] = sq;
  }

  {
    char* lp = sm + BUF0_OFF + lds_woff;
#pragma unroll
    for (int s = 0; s < 4; ++s)
      load_lds16(gbase + (size_t)(s * 16) * DIM, lp + s * 1024);
  }
  __syncthreads();

#pragma unroll 2
  for (int ch = 0; ch < NCH; ++ch) {
    const int cb  = (ch & 1) ? BUF1_OFF : BUF0_OFF;
    const int nbo = (ch & 1) ? BUF0_OFF : BUF1_OFF;
    if (ch < NCH - 1) {
      char* lp = sm + nbo + lds_woff;
      const ushort* gp = gbase + (ch + 1) * BK;
#pragma unroll
      for (int s = 0; s < 4; ++s)
        load_lds16(gp + (size_t)(s * 16) * DIM, lp + s * 1024);
    }

    const ushort* sA = (const ushort*)(sm + cb);
    const ushort* sB = (const ushort*)(sm + cb + 8192);

    short8 a[4], b[4];
#pragma unroll
    for (int f = 0; f < 4; ++f) {
      a[f] = *(const short8*)&sA[(wr * 64 + f * 16 + (L & 15)) * BK + slot8];
      b[f] = *(const short8*)&sB[(wc * 64 + f * 16 + (L & 15)) * BK + slot8];
    }
#pragma unroll
    for (int fj = 0; fj < 4; ++fj)
#pragma unroll
      for (int fi = 0; fi < 4; ++fi)
        acc[fj][fi] = __builtin_amdgcn_mfma_f32_16x16x32_bf16(b[fj], a[fi], acc[fj][fi], 0, 0, 0);
    __syncthreads();
  }

#pragma unroll
  for (int fj = 0; fj < 4; ++fj)
#pragma unroll
    for (int fi = 0; fi < 4; ++fi) {
      const int i_t = wr * 64 + fi * 16 + (L & 15);
      const int jd  = wc * 32 + fj * 8 + (L >> 4) * 2;
      uint32 dw0, dw1;
      asm("v_cvt_pk_bf16_f32 %0, %1, %2" : "=v"(dw0) : "v"(acc[fj][fi][0]), "v"(acc[fj][fi][1]));
      asm("v_cvt_pk_bf16_f32 %0, %1, %2" : "=v"(dw1) : "v"(acc[fj][fi][2]), "v"(acc[fj][fi][3]));
      uint2 d2; d2.x = dw0; d2.y = dw1;
      *(uint2*)&sdp[i_t * SDW + jd] = d2;
    }
  __syncthreads();

  uint32 tau_cur = EMPTYK;
  const int selfc = gi - j0p;
  if (selfc >= 0 && selfc < JS && h == (selfc >> 6))
    *(ushort*)(sm + myrow * (SDW * 4) + selfc * 2) = 0x7F80;

  const uint32* rowp = sdp + myrow * SDW + 32 * h;
  const uint32 jb = (uint32)(j0p + 64 * h);
  uint32 guard = min(tau_cur, td[14]);
  uint32 nc = 0;
  uint32 p0=0,p1=0,p2=0,p3=0,p4=0,p5=0,p6=0,p7=0,p8=0,p9=0,p10=0,p11=0;

#pragma unroll 2
  for (int q = 0; q < 8; ++q) {
    const uint4 pv = *(const uint4*)&rowp[4 * q];
    const uint32 jq = jb + 8 * q;
    uint32 kx;
    kx = (pv.x << 16)          | (jq + 0); if (kx < guard) PUSHK(kx);
    kx = (pv.x & 0xFFFF0000u)  | (jq + 1); if (kx < guard) PUSHK(kx);
    kx = (pv.y << 16)          | (jq + 2); if (kx < guard) PUSHK(kx);
    kx = (pv.y & 0xFFFF0000u)  | (jq + 3); if (kx < guard) PUSHK(kx);
    kx = (pv.z << 16)          | (jq + 4); if (kx < guard) PUSHK(kx);
    kx = (pv.z & 0xFFFF0000u)  | (jq + 5); if (kx < guard) PUSHK(kx);
    kx = (pv.w << 16)          | (jq + 6); if (kx < guard) PUSHK(kx);
    kx = (pv.w & 0xFFFF0000u)  | (jq + 7); if (kx < guard) PUSHK(kx);
    if (__any(nc >= 4)) { DRAINALL; }
  }
  if (__any(nc > 0)) { DRAINALL; }
  __syncthreads();

  uint32* mdk = (uint32*)sm;
#pragma unroll
  for (int p = 0; p < 15; ++p) mdk[(myrow * 2 + h) * 15 + p] = td[p];
  __syncthreads();
  if (h == 0) {
    const uint32* la = &mdk[(myrow * 2 + 0) * 15];
    const uint32* lb = &mdk[(myrow * 2 + 1) * 15];
    int pa = 0, pb = 0;
    const size_t base = ((size_t)gi * NLIST + blockIdx.y) * KNNK;
    for (int s = 0; s < KNNK; ++s) {
      const uint32 va = la[pa], vb = lb[pb];
      uint32 v;
      if (va <= vb) { v = va; ++pa; } else { v = vb; ++pb; }
      knnk[base + s] = v;
    }
  }
}

// ---------------------------------------------------------------- tau
// One WAVE per point: coalesced load of 240 probe keys (4/lane), 15
// extract-min rounds -> EXACT 15th of the probe region (2048 pts) + margin.
__global__ __launch_bounds__(256) void tau_kernel(
    const uint32* __restrict__ knnk, uint32* __restrict__ tauk) {
  const int wid = threadIdx.x >> 6;
  const int L   = threadIdx.x & 63;
  const int p   = blockIdx.x * 4 + wid;
  const uint32* kl = knnk + (size_t)p * NKEYS;
  uint32 v0 = kl[L];
  uint32 v1 = kl[L + 64];
  uint32 v2 = kl[L + 128];
  uint32 v3 = (L < NPKEYS - 192) ? kl[L + 192] : EMPTYK;   // 192..239
  uint32 last = EMPTYK;
  for (int sel = 0; sel < KNNK; ++sel) {
    uint32 v = v0; int which = 0;
    if (v1 < v) { v = v1; which = 1; }
    if (v2 < v) { v = v2; which = 2; }
    if (v3 < v) { v = v3; which = 3; }
    int slot = (L << 2) | which;
#pragma unroll
    for (int off = 32; off > 0; off >>= 1) {
      const uint32 ov = (uint32)__shfl_down((int)v, off, 64);
      const int    os = __shfl_down(slot, off, 64);
      if (ov < v) { v = ov; slot = os; }
    }
    const uint32 vmin = (uint32)__shfl((int)v, 0, 64);
    const int    smin = __shfl(slot, 0, 64);
    if (sel == KNNK - 1) last = vmin;
    if (L == (smin >> 2)) {
      const int wsel = smin & 3;
      if (wsel == 0) v0 = EMPTYK;
      else if (wsel == 1) v1 = EMPTYK;
      else if (wsel == 2) v2 = EMPTYK;
      else v3 = EMPTYK;
    }
  }
  if (L == 0) tauk[p] = last + TAU_MARGIN;
}

// ---------------------------------------------------------------- main
// Splits 4..15; tau read as a single precomputed value per row.
__global__ __launch_bounds__(256, 4) void knn_main(
    const ushort* __restrict__ EA, const ushort* __restrict__ EB,
    const float* __restrict__ sqn, const uint32* __restrict__ tauk,
    uint32* __restrict__ knnk) {
  __shared__ __align__(16) char sm[KNN_LDS];
  uint32* sdp  = (uint32*)sm;
  float*  sqjs = (float*)(sm + SQJ_OFF);

  const int tid = threadIdx.x;
  const int w   = tid >> 6;
  const int L   = tid & 63;
  const int wr  = (w >> 1) & 1;
  const int wc  = w & 1;
  const int i0  = blockIdx.x * NI;
  const int jsplit = blockIdx.y + 4;
  const int j0  = jsplit * NJ;

  if (tid < NJ / 4) ((float4*)sqjs)[tid] = ((const float4*)(sqn + j0))[tid];

  const ushort* gsrc = (w < 2) ? EA : EB;
  const int lrow  = L >> 2;
  const int swz_k = ((L & 3) ^ ((L >> 3) & 3)) * 8;
  const int lds_woff = ((w < 2) ? 0 : 8192) + (w & 1) * 4096;
  const int slot8 = (((L >> 4) ^ ((L >> 1) & 3)) * 8);

  const int myrow = tid >> 1;
  const int h     = tid & 1;
  const int gi    = i0 + myrow;

  const uint32 tauA = tauk[gi];

  uint32 td[15];
#pragma unroll
  for (int p = 0; p < 15; ++p) td[p] = EMPTYK;

  __syncthreads();

  for (int js = 0; js < NSUB; ++js) {
    const int jrow0 = j0 + js * JS;
    const int trowW = ((w < 2) ? i0 : jrow0) + (w & 1) * 64;
    const ushort* gbase = gsrc + (size_t)(trowW + lrow) * DIM + swz_k;

    f32x4 acc[4][4];
#pragma unroll
    for (int fj = 0; fj < 4; ++fj) {
      const f32x4 sq = *(const f32x4*)&sqjs[js * 128 + wc * 64 + fj * 16 + (L >> 4) * 4];
#pragma unroll
      for (int fi = 0; fi < 4; ++fi) acc[fj][fi] = sq;
    }

    {
      char* lp = sm + BUF0_OFF + lds_woff;
#pragma unroll
      for (int s = 0; s < 4; ++s)
        load_lds16(gbase + (size_t)(s * 16) * DIM, lp + s * 1024);
    }
    __syncthreads();

#pragma unroll 2
    for (int ch = 0; ch < NCH; ++ch) {
      const int cb  = (ch & 1) ? BUF1_OFF : BUF0_OFF;
      const int nbo = (ch & 1) ? BUF0_OFF : BUF1_OFF;
      if (ch < NCH - 1) {
        char* lp = sm + nbo + lds_woff;
        const ushort* gp = gbase + (ch + 1) * BK;
#pragma unroll
        for (int s = 0; s < 4; ++s)
          load_lds16(gp + (size_t)(s * 16) * DIM, lp + s * 1024);
      }

      const ushort* sA = (const ushort*)(sm + cb);
      const ushort* sB = (const ushort*)(sm + cb + 8192);

      short8 a[4], b[4];
#pragma unroll
      for (int f = 0; f < 4; ++f) {
        a[f] = *(const short8*)&sA[(wr * 64 + f * 16 + (L & 15)) * BK + slot8];
        b[f] = *(const short8*)&sB[(wc * 64 + f * 16 + (L & 15)) * BK + slot8];
      }
#pragma unroll
      for (int fj = 0; fj < 4; ++fj)
#pragma unroll
        for (int fi = 0; fi < 4; ++fi)
          acc[fj][fi] = __builtin_amdgcn_mfma_f32_16x16x32_bf16(b[fj], a[fi], acc[fj][fi], 0, 0, 0);
      __syncthreads();
    }

#pragma unroll
    for (int fj = 0; fj < 4; ++fj)
#pragma unroll
      for (int fi = 0; fi < 4; ++fi) {
        const int i_t = wr * 64 + fi * 16 + (L & 15);
        const int jd  = wc * 32 + fj * 8 + (L >> 4) * 2;
        uint32 dw0, dw1;
        asm("v_cvt_pk_bf16_f32 %0, %1, %2" : "=v"(dw0) : "v"(acc[fj][fi][0]), "v"(acc[fj][fi][1]));
        asm("v_cvt_pk_bf16_f32 %0, %1, %2" : "=v"(dw1) : "v"(acc[fj][fi][2]), "v"(acc[fj][fi][3]));
        uint2 d2; d2.x = dw0; d2.y = dw1;
        *(uint2*)&sdp[i_t * SDW + jd] = d2;
      }
    __syncthreads();

    uint32 tau_cur = tauA;
    const int selfc = gi - jrow0;
    if (selfc >= 0 && selfc < JS && h == (selfc >> 6))
      *(ushort*)(sm + myrow * (SDW * 4) + selfc * 2) = 0x7F80;

    const uint32* rowp = sdp + myrow * SDW + 32 * h;
    const uint32 jb = (uint32)(jrow0 + 64 * h);
    uint32 guard = min(tau_cur, td[14]);
    uint32 nc = 0;
    uint32 p0=0,p1=0,p2=0,p3=0,p4=0,p5=0,p6=0,p7=0,p8=0,p9=0,p10=0,p11=0;

#pragma unroll 2
    for (int q = 0; q < 8; ++q) {
      const uint4 pv = *(const uint4*)&rowp[4 * q];
      const uint32 jq = jb + 8 * q;
      uint32 kx;
      kx = (pv.x << 16)          | (jq + 0); if (kx < guard) PUSHK(kx);
      kx = (pv.x & 0xFFFF0000u)  | (jq + 1); if (kx < guard) PUSHK(kx);
      kx = (pv.y << 16)          | (jq + 2); if (kx < guard) PUSHK(kx);
      kx = (pv.y & 0xFFFF0000u)  | (jq + 3); if (kx < guard) PUSHK(kx);
      kx = (pv.z << 16)          | (jq + 4); if (kx < guard) PUSHK(kx);
      kx = (pv.z & 0xFFFF0000u)  | (jq + 5); if (kx < guard) PUSHK(kx);
      kx = (pv.w << 16)          | (jq + 6); if (kx < guard) PUSHK(kx);
      kx = (pv.w & 0xFFFF0000u)  | (jq + 7); if (kx < guard) PUSHK(kx);
      if (__any(nc >= 4)) { DRAINALL; }
    }
    if (__any(nc > 0)) { DRAINALL; }
    __syncthreads();
  }

  uint32* mdk = (uint32*)sm;
#pragma unroll
  for (int p = 0; p < 15; ++p) mdk[(myrow * 2 + h) * 15 + p] = td[p];
  __syncthreads();
  if (h == 0) {
    const uint32* la = &mdk[(myrow * 2 + 0) * 15];
    const uint32* lb = &mdk[(myrow * 2 + 1) * 15];
    int pa = 0, pb = 0;
    const size_t base = ((size_t)gi * NLIST + NPROBE + blockIdx.y) * KNNK;
    for (int s = 0; s < KNNK; ++s) {
      const uint32 va = la[pa], vb = lb[pb];
      uint32 v;
      if (va <= vb) { v = va; ++pa; } else { v = vb; ++pb; }
      knnk[base + s] = v;
    }
  }
}

// ---------------------------------------------------------------- sig
// 420 keys (28 lists): radix-select rank-21 threshold (ballot+popc),
// ballot-prefix compaction, parallel coalesced refine, rank sort, gram,
// bitonic-128.
__global__ __launch_bounds__(256) void sig_kernel(
    const float* __restrict__ E, const uint32* __restrict__ knnk,
    const float* __restrict__ refc, const float* __restrict__ refa,
    float2* __restrict__ pacc) {
  __shared__ float gsm[4][352];  // gram 0..271 | inv 272..287 | cand 288..311
                                 // dsel 312..326 | nbr 328..342

  const int tid = threadIdx.x;
  const int wid = tid >> 6;
  const int L   = tid & 63;
  const int i   = blockIdx.x * 4 + wid;

  const uint32* kl = knnk + (size_t)i * NKEYS;   // 420 keys
  const uint32 k0 = kl[L];
  const uint32 k1 = kl[L + 64];
  const uint32 k2 = kl[L + 128];
  const uint32 k3 = kl[L + 192];
  const uint32 k4 = kl[L + 256];
  const uint32 k5 = kl[L + 320];                 // 320..383 < 420
  const uint32 k6 = (L < NKEYS - 384) ? kl[L + 384] : EMPTYK;  // 384..419

  // ---- radix-select the rank-(NCAND-1) key T (max T with count(<T)<=21)
  uint32 T = 0;
  for (int b = 31; b >= 0; --b) {
    const uint32 Tt = T | (1u << b);
    const int cnt = __popcll(__ballot(k0 < Tt)) + __popcll(__ballot(k1 < Tt)) +
                    __popcll(__ballot(k2 < Tt)) + __popcll(__ballot(k3 < Tt)) +
                    __popcll(__ballot(k4 < Tt)) + __popcll(__ballot(k5 < Tt)) +
                    __popcll(__ballot(k6 < Tt));
    if (cnt <= NCAND - 1) T = Tt;
  }

  // ---- compact the exactly-NCAND keys <= T into LDS via ballot-prefix
  uint32* candL = (uint32*)&gsm[wid][288];
  {
    const unsigned long long B0 = __ballot(k0 <= T);
    const unsigned long long B1 = __ballot(k1 <= T);
    const unsigned long long B2 = __ballot(k2 <= T);
    const unsigned long long B3 = __ballot(k3 <= T);
    const unsigned long long B4 = __ballot(k4 <= T);
    const unsigned long long B5 = __ballot(k5 <= T);
    const unsigned long long B6 = __ballot(k6 <= T);
    int off = 0;
    if (k0 <= T) candL[off + lanes_below(B0)] = k0;
    off += __popcll(B0);
    if (k1 <= T) candL[off + lanes_below(B1)] = k1;
    off += __popcll(B1);
    if (k2 <= T) candL[off + lanes_below(B2)] = k2;
    off += __popcll(B2);
    if (k3 <= T) candL[off + lanes_below(B3)] = k3;
    off += __popcll(B3);
    if (k4 <= T) candL[off + lanes_below(B4)] = k4;
    off += __popcll(B4);
    if (k5 <= T) candL[off + lanes_below(B5)] = k5;
    off += __popcll(B5);
    if (k6 <= T) candL[off + lanes_below(B6)] = k6;
  }
  asm volatile("s_waitcnt lgkmcnt(0)" ::: "memory");
  const uint32 cand_key = (L < NCAND) ? candL[L] : EMPTYK;
  int cand_nb = ((cand_key >> 16) < 0x7F80u) ? (int)(cand_key & 0x1FFFu) : i;

  // ---- parallel exact refine: round r covers candidates r*8+g,
  //      group g = L>>3; lane u = L&7 reads float4s u+8t (coalesced).
  const float* Ei = E + (size_t)i * DIM;
  const int u = L & 7;
  const int g = L >> 3;
  float sr[3];
#pragma unroll
  for (int r = 0; r < 3; ++r) {
    const int c = r * 8 + g;                    // 0..23
    const int row = __shfl(cand_nb, c, 64);     // sentinel i for c>=22
    const float4* r4 = (const float4*)(E + (size_t)row * DIM);
    const float4* e4 = (const float4*)Ei;
    float a0 = 0.f, a1 = 0.f, a2 = 0.f, a3 = 0.f;
#pragma unroll
    for (int t = 0; t < 16; ++t) {
      const float4 av = r4[u + 8 * t];
      const float4 ev = e4[u + 8 * t];
      const float d0 = av.x - ev.x, d1 = av.y - ev.y;
      const float d2 = av.z - ev.z, d3 = av.w - ev.w;
      a0 = fmaf(d0, d0, a0); a1 = fmaf(d1, d1, a1);
      a2 = fmaf(d2, d2, a2); a3 = fmaf(d3, d3, a3);
    }
    float s = (a0 + a1) + (a2 + a3);
    s += __shfl_xor(s, 1, 64);
    s += __shfl_xor(s, 2, 64);
    s += __shfl_xor(s, 4, 64);
    sr[r] = s;
  }
  const int srcl = (L & 7) * 8;
  const float t0 = __shfl(sr[0], srcl, 64);
  const float t1 = __shfl(sr[1], srcl, 64);
  const float t2 = __shfl(sr[2], srcl, 64);
  float csq = (L >> 3) == 0 ? t0 : ((L >> 3) == 1 ? t1 : t2);
  if (L >= NCAND || cand_nb == i) csq = CINF;

  // ---- rank sort: NCAND independent readlane compares -> LDS rank slot
  int rank = 0;
#pragma unroll
  for (int j = 0; j < NCAND; ++j) {
    const float vj = __shfl(csq, j, 64);
    rank += (vj < csq) || (vj == csq && j < L);
  }
  float* dselL = &gsm[wid][312];
  int*   nbrL  = (int*)&gsm[wid][328];
  if (L < NCAND && rank < KNNK) { dselL[rank] = csq; nbrL[rank] = cand_nb; }
  asm volatile("s_waitcnt lgkmcnt(0)" ::: "memory");
  const int sel = L & 15;
  const int mynb = (sel < KNNK) ? nbrL[sel] : i;
  const float myd = (L < KNNK) ? sqrtf(fmaxf(dselL[L], 1e-12f)) : 0.f;

  // ---- curvature (lanes 0..14 hold ranks 0..14)
  float curvs;
  {
    float dd = (L < KNNK) ? myd : 0.f;
    float tot = wave_sum_f(dd);
    float mean_d = tot / (float)KNNK + 1e-8f;
    float diff = (L < KNNK) ? (dd / mean_d - refc[i * KNNK + L]) : 0.f;
    curvs = wave_sum_f(diff * diff);
  }

  // ---- gram of raw neighbor differences (row = L&15; row 15 = self -> zero)
  const float4* nb4 = (const float4*)(E + (size_t)mynb * DIM);
  const float4* ei4 = (const float4*)Ei;
  const int qo = (L >> 4) * 2;

  f32x4 gH, gX1, gX2;
#pragma unroll
  for (int r = 0; r < 4; ++r) { gH[r] = 0.f; gX1[r] = 0.f; gX2[r] = 0.f; }

#pragma unroll
  for (int c = 0; c < 16; ++c) {
    const float4 f0 = nb4[qo + c * 8];
    const float4 f1 = nb4[qo + 1 + c * 8];
    const float4 g0 = ei4[qo + c * 8];
    const float4 g1 = ei4[qo + 1 + c * 8];
    float v[8];
    v[0] = f0.x - g0.x; v[1] = f0.y - g0.y; v[2] = f0.z - g0.z; v[3] = f0.w - g0.w;
    v[4] = f1.x - g1.x; v[5] = f1.y - g1.y; v[6] = f1.z - g1.z; v[7] = f1.w - g1.w;
    short8 ah, al;
#pragma unroll
    for (int q = 0; q < 8; ++q) {
      short hh, ll;
      bf16split(v[q], hh, ll);
      ah[q] = hh; al[q] = ll;
    }
    gH  = __builtin_amdgcn_mfma_f32_16x16x32_bf16(ah, ah, gH, 0, 0, 0);
    gX1 = __builtin_amdgcn_mfma_f32_16x16x32_bf16(ah, al, gX1, 0, 0, 0);
    gX2 = __builtin_amdgcn_mfma_f32_16x16x32_bf16(al, ah, gX2, 0, 0, 0);
  }

#pragma unroll
  for (int q = 0; q < 4; ++q)
    gsm[wid][((L >> 4) * 4 + q) * 17 + (L & 15)] = gH[q] + gX1[q] + gX2[q];
  asm volatile("s_waitcnt lgkmcnt(0)" ::: "memory");

  if (L < 16) {
    const float dv = gsm[wid][L * 17 + L];
    const float nrm = sqrtf(fmaxf(dv, 0.f));
    gsm[wid][272 + L] = 1.0f / fmaxf(nrm, 1e-8f);
  }
  asm volatile("s_waitcnt lgkmcnt(0)" ::: "memory");

  float c0 = CINF, c1 = CINF;
#pragma unroll
  for (int s = 0; s < 2; ++s) {
    const int p = L + 64 * s;
    if (p < NPAIR) {
      int a = 0, rem = p, cnt = 14;
      while (rem >= cnt) { rem -= cnt; --cnt; ++a; }
      const int b = a + 1 + rem;
      const float cv = gsm[wid][a * 17 + b] * gsm[wid][272 + a] * gsm[wid][272 + b];
      if (s == 0) c0 = cv; else c1 = cv;
    }
  }

  // bitonic-128 ascending
#pragma unroll
  for (int k = 2; k <= 128; k <<= 1) {
#pragma unroll
    for (int j = k >> 1; j >= 1; j >>= 1) {
      const bool dir = ((L & (k >> 1)) == 0);
      if (j == 1) {
        const float lo = fminf(c0, c1), hi = fmaxf(c0, c1);
        c0 = dir ? lo : hi;
        c1 = dir ? hi : lo;
      } else {
        const int m = j >> 1;
        const float o0 = __shfl_xor(c0, m, 64);
        const float o1 = __shfl_xor(c1, m, 64);
        const bool lower = ((L & m) == 0);
        c0 = (lower == dir) ? fminf(c0, o0) : fmaxf(c0, o0);
        c1 = (lower == dir) ? fminf(c1, o1) : fmaxf(c1, o1);
      }
    }
  }

  float part = 0.f;
  {
    const int r0 = 2 * L, r1 = 2 * L + 1;
    if (r0 < NPAIR) { const float dd = c0 - refa[(size_t)i * NPAIR + r0]; part += dd * dd; }
    if (r1 < NPAIR) { const float dd = c1 - refa[(size_t)i * NPAIR + r1]; part += dd * dd; }
  }
  part = wave_sum_f(part);
  if (L == 0) pacc[i] = make_float2(curvs, part);
}

// ---------------------------------------------------------------- fin
__global__ __launch_bounds__(256) void fin_kernel(
    const float2* __restrict__ pacc, float* __restrict__ out) {
  __shared__ double redc[4], reda[4];
  const int tid = threadIdx.x;
  const int wid = tid >> 6;
  const int L   = tid & 63;
  double sc = 0.0, sa = 0.0;
#pragma unroll
  for (int q = 0; q < 32; ++q) {
    const float2 p = pacc[tid + 256 * q];
    sc += (double)p.x;
    sa += (double)p.y;
  }
#pragma unroll
  for (int m = 32; m > 0; m >>= 1) {
    sc += __shfl_xor(sc, m, 64);
    sa += __shfl_xor(sa, m, 64);
  }
  if (L == 0) { redc[wid] = sc; reda[wid] = sa; }
  __syncthreads();
  if (tid == 0) {
    const double curv = (redc[0] + redc[1] + redc[2] + redc[3]) /
                        ((double)NPTS * (double)KNNK);
    const double ang  = (reda[0] + reda[1] + reda[2] + reda[3]) /
                        ((double)NPTS * (double)NPAIR);
    out[0] = (float)(0.3 * curv + 0.7 * ang);
  }
}

// ---------------------------------------------------------------- launch
extern "C" void kernel_launch(void* const* d_in, const int* in_sizes, int n_in,
                              void* d_out, int out_size, void* d_ws,
                              size_t ws_size, hipStream_t stream) {
  const float* E    = (const float*)d_in[0];
  const float* refc = (const float*)d_in[1];
  const float* refa = (const float*)d_in[2];
  float* out = (float*)d_out;

  char* ws = (char*)d_ws;
  float*  sqn  = (float*)(ws + 1024);
  float2* pacc = (float2*)(ws + 65536);
  uint32* tauk = (uint32*)(ws + 131072);      // [NPTS]
  ushort* EA   = (ushort*)(ws + 1048576);
  ushort* EB   = (ushort*)(ws + 9437184);
  uint32* knnk = (uint32*)(ws + 17825792);    // [NPTS][28][15] keys (13.8 MB)

  prep_kernel<<<NPTS / 4, 256, 0, stream>>>(E, sqn, EA, EB);
  knn_probe<<<dim3(NPTS / NI, NPROBE), 256, 0, stream>>>(EA, EB, sqn, knnk);
  tau_kernel<<<NPTS / 4, 256, 0, stream>>>(knnk, tauk);
  knn_main<<<dim3(NPTS / NI, NMAIN), 256, 0, stream>>>(EA, EB, sqn, tauk, knnk);
  sig_kernel<<<NPTS / 4, 256, 0, stream>>>(E, knnk, refc, refa, pacc);
  fin_kernel<<<1, 256, 0, stream>>>(pacc, out);
}

// Round 13
// 277.856 us; speedup vs baseline: 1.0440x; 1.0440x over previous
//
#include <hip/hip_runtime.h>
#include <hip/hip_bf16.h>
#include <math.h>

#define NPTS  8192
#define DIM   512
#define KNNK  15
#define NCAND 22
#define NPAIR 105
#define CINF  3.0e38f
#define EMPTYK 0xFFFFFFFFu
#define TAU_MARGIN (3u << 16)   // +3 bf16 ulp on the screen threshold

// knn tiling: one split (128 x 512) per block; grid 64x16 = 1024 = 4/CU
#define NI      128
#define NJSPLIT 16
#define NJ      (NPTS/NJSPLIT)   // 512
#define JS      128
#define NSUB    (NJ/JS)          // 4
#define BK      32
#define NCH     (DIM/BK)         // 16 chunks, double-buffered
#define SDW     68               // packed sdist row stride in dwords
#define NLIST   NJSPLIT          // 16 lists per point
#define NKEYS   (NLIST * KNNK)   // 240 keys per point

// knn LDS byte map (39936 B -> 4 blocks/CU)
#define BUF0_OFF   0
#define BUF1_OFF   16384
#define SQJ_OFF    34816
#define KNN_LDS    39936

typedef __attribute__((ext_vector_type(8))) short short8;
typedef __attribute__((ext_vector_type(4))) float f32x4;
typedef unsigned int uint32;

static __device__ __forceinline__ float wave_sum_f(float v) {
#pragma unroll
  for (int m = 32; m > 0; m >>= 1) v += __shfl_xor(v, m, 64);
  return v;
}

static __device__ __forceinline__ void load_lds16(const void* g, void* l) {
  __builtin_amdgcn_global_load_lds(
      (const __attribute__((address_space(1))) void*)g,
      (__attribute__((address_space(3))) void*)l, 16, 0, 0);
}

static __device__ __forceinline__ void bf16split(float x, short& h, short& l) {
  __hip_bfloat16 hb = __float2bfloat16(x);
  const float hf = __bfloat162float(hb);
  __hip_bfloat16 lb = __float2bfloat16(x - hf);
  h = *(short*)&hb;
  l = *(short*)&lb;
}

// # of set bits of B strictly below this lane
static __device__ __forceinline__ int lanes_below(unsigned long long B) {
  int c = __builtin_amdgcn_mbcnt_lo((uint32)B, 0);
  return __builtin_amdgcn_mbcnt_hi((uint32)(B >> 32), c);
}

// sorted-ascending insert of key c into td[0..14]
static __device__ __forceinline__ void chain15(uint32 (&td)[15], uint32 c) {
#pragma unroll
  for (int p = 0; p < 15; ++p) {
    const uint32 lo = min(c, td[p]);
    const uint32 hi = max(c, td[p]);
    td[p] = lo; c = hi;
  }
}

#define PUSHK(k_) { const uint32 kv_ = (k_); \
  p0=(nc==0)?kv_:p0;  p1=(nc==1)?kv_:p1;  p2=(nc==2)?kv_:p2; \
  p3=(nc==3)?kv_:p3;  p4=(nc==4)?kv_:p4;  p5=(nc==5)?kv_:p5; \
  p6=(nc==6)?kv_:p6;  p7=(nc==7)?kv_:p7;  p8=(nc==8)?kv_:p8; \
  p9=(nc==9)?kv_:p9;  p10=(nc==10)?kv_:p10; p11=(nc==11)?kv_:p11; \
  ++nc; }

#define DRAINALL { \
  if (__any(nc >  0)) { if (nc >  0) chain15(td, p0);  } \
  if (__any(nc >  1)) { if (nc >  1) chain15(td, p1);  } \
  if (__any(nc >  2)) { if (nc >  2) chain15(td, p2);  } \
  if (__any(nc >  3)) { if (nc >  3) chain15(td, p3);  } \
  if (__any(nc >  4)) { if (nc >  4) chain15(td, p4);  } \
  if (__any(nc >  5)) { if (nc >  5) chain15(td, p5);  } \
  if (__any(nc >  6)) { if (nc >  6) chain15(td, p6);  } \
  if (__any(nc >  7)) { if (nc >  7) chain15(td, p7);  } \
  if (__any(nc >  8)) { if (nc >  8) chain15(td, p8);  } \
  if (__any(nc >  9)) { if (nc >  9) chain15(td, p9);  } \
  if (__any(nc > 10)) { if (nc > 10) chain15(td, p10); } \
  if (__any(nc > 11)) { if (nc > 11) chain15(td, p11); } \
  nc = 0; guard = min(tau_cur, td[14]); }

// ---------------------------------------------------------------- prep
__global__ __launch_bounds__(256) void prep_kernel(
    const float* __restrict__ E, float* __restrict__ sqn,
    ushort* __restrict__ EA, ushort* __restrict__ EB,
    uint32* __restrict__ tauk) {
  const int row  = blockIdx.x * 4 + (threadIdx.x >> 6);
  const int lane = threadIdx.x & 63;
  const float SR2 = 1.4142135623730951f;
  float s = 0.f;
#pragma unroll
  for (int c = 0; c < 8; ++c) {
    const int d0 = lane + 64 * c;
    const float x = E[(size_t)row * DIM + d0];
    s = fmaf(x, x, s);
    __hip_bfloat16 ha = __float2bfloat16(-SR2 * x);
    __hip_bfloat16 hb = __float2bfloat16( SR2 * x);
    EA[(size_t)row * DIM + d0] = *(ushort*)&ha;
    EB[(size_t)row * DIM + d0] = *(ushort*)&hb;
  }
  s = wave_sum_f(s);
  if (lane == 0) { sqn[row] = s; tauk[row] = EMPTYK; }
}

// ---------------------------------------------------------------- knn
// FUSED screen: probe/tau/main in one launch. tau is a device-global
// monotone bound shared via atomicMin; each subtile scan reads it fresh
// (stale reads are safe: tau only decreases) and publishes its own row
// 15th+margin afterwards. All 1024 blocks co-resident (4/CU): after the
// first subtile generation, tau ~ 15th-of-2048-sample for every row.
__global__ __launch_bounds__(256, 4) void knn_kernel(
    const ushort* __restrict__ EA, const ushort* __restrict__ EB,
    const float* __restrict__ sqn, uint32* __restrict__ tauk,
    uint32* __restrict__ knnk) {
  __shared__ __align__(16) char sm[KNN_LDS];
  uint32* sdp  = (uint32*)sm;
  float*  sqjs = (float*)(sm + SQJ_OFF);

  const int tid = threadIdx.x;
  const int w   = tid >> 6;
  const int L   = tid & 63;
  const int wr  = (w >> 1) & 1;
  const int wc  = w & 1;
  const int i0  = blockIdx.x * NI;
  const int jsplit = blockIdx.y;
  const int j0  = jsplit * NJ;

  if (tid < NJ / 4) ((float4*)sqjs)[tid] = ((const float4*)(sqn + j0))[tid];

  const ushort* gsrc = (w < 2) ? EA : EB;
  const int lrow  = L >> 2;
  const int swz_k = ((L & 3) ^ ((L >> 3) & 3)) * 8;
  const int lds_woff = ((w < 2) ? 0 : 8192) + (w & 1) * 4096;
  const int slot8 = (((L >> 4) ^ ((L >> 1) & 3)) * 8);

  const int myrow = tid >> 1;
  const int h     = tid & 1;
  const int gi    = i0 + myrow;

  uint32 td[15];
#pragma unroll
  for (int p = 0; p < 15; ++p) td[p] = EMPTYK;

  __syncthreads();

  for (int js = 0; js < NSUB; ++js) {
    const int jrow0 = j0 + js * JS;
    const int trowW = ((w < 2) ? i0 : jrow0) + (w & 1) * 64;
    const ushort* gbase = gsrc + (size_t)(trowW + lrow) * DIM + swz_k;

    f32x4 acc[4][4];
#pragma unroll
    for (int fj = 0; fj < 4; ++fj) {
      const f32x4 sq = *(const f32x4*)&sqjs[js * 128 + wc * 64 + fj * 16 + (L >> 4) * 4];
#pragma unroll
      for (int fi = 0; fi < 4; ++fi) acc[fj][fi] = sq;
    }

    {
      char* lp = sm + BUF0_OFF + lds_woff;
#pragma unroll
      for (int s = 0; s < 4; ++s)
        load_lds16(gbase + (size_t)(s * 16) * DIM, lp + s * 1024);
    }
    __syncthreads();

#pragma unroll 2
    for (int ch = 0; ch < NCH; ++ch) {
      const int cb  = (ch & 1) ? BUF1_OFF : BUF0_OFF;
      const int nbo = (ch & 1) ? BUF0_OFF : BUF1_OFF;
      if (ch < NCH - 1) {
        char* lp = sm + nbo + lds_woff;
        const ushort* gp = gbase + (ch + 1) * BK;
#pragma unroll
        for (int s = 0; s < 4; ++s)
          load_lds16(gp + (size_t)(s * 16) * DIM, lp + s * 1024);
      }

      const ushort* sA = (const ushort*)(sm + cb);
      const ushort* sB = (const ushort*)(sm + cb + 8192);

      short8 a[4], b[4];
#pragma unroll
      for (int f = 0; f < 4; ++f) {
        a[f] = *(const short8*)&sA[(wr * 64 + f * 16 + (L & 15)) * BK + slot8];
        b[f] = *(const short8*)&sB[(wc * 64 + f * 16 + (L & 15)) * BK + slot8];
      }
#pragma unroll
      for (int fj = 0; fj < 4; ++fj)
#pragma unroll
        for (int fi = 0; fi < 4; ++fi)
          acc[fj][fi] = __builtin_amdgcn_mfma_f32_16x16x32_bf16(b[fj], a[fi], acc[fj][fi], 0, 0, 0);
      __syncthreads();
    }

#pragma unroll
    for (int fj = 0; fj < 4; ++fj)
#pragma unroll
      for (int fi = 0; fi < 4; ++fi) {
        const int i_t = wr * 64 + fi * 16 + (L & 15);
        const int jd  = wc * 32 + fj * 8 + (L >> 4) * 2;
        uint32 dw0, dw1;
        asm("v_cvt_pk_bf16_f32 %0, %1, %2" : "=v"(dw0) : "v"(acc[fj][fi][0]), "v"(acc[fj][fi][1]));
        asm("v_cvt_pk_bf16_f32 %0, %1, %2" : "=v"(dw1) : "v"(acc[fj][fi][2]), "v"(acc[fj][fi][3]));
        uint2 d2; d2.x = dw0; d2.y = dw1;
        *(uint2*)&sdp[i_t * SDW + jd] = d2;
      }
    __syncthreads();

    // fresh monotone tau (stale value = weaker guard, still correct)
    const uint32 tau_cur = __hip_atomic_load(&tauk[gi], __ATOMIC_RELAXED,
                                             __HIP_MEMORY_SCOPE_AGENT);
    const int selfc = gi - jrow0;
    if (selfc >= 0 && selfc < JS && h == (selfc >> 6))
      *(ushort*)(sm + myrow * (SDW * 4) + selfc * 2) = 0x7F80;

    const uint32* rowp = sdp + myrow * SDW + 32 * h;
    const uint32 jb = (uint32)(jrow0 + 64 * h);
    uint32 guard = min(tau_cur, td[14]);
    uint32 nc = 0;
    uint32 p0=0,p1=0,p2=0,p3=0,p4=0,p5=0,p6=0,p7=0,p8=0,p9=0,p10=0,p11=0;

#pragma unroll 2
    for (int q = 0; q < 8; ++q) {
      const uint4 pv = *(const uint4*)&rowp[4 * q];
      const uint32 jq = jb + 8 * q;
      uint32 kx;
      kx = (pv.x << 16)          | (jq + 0); if (kx < guard) PUSHK(kx);
      kx = (pv.x & 0xFFFF0000u)  | (jq + 1); if (kx < guard) PUSHK(kx);
      kx = (pv.y << 16)          | (jq + 2); if (kx < guard) PUSHK(kx);
      kx = (pv.y & 0xFFFF0000u)  | (jq + 3); if (kx < guard) PUSHK(kx);
      kx = (pv.z << 16)          | (jq + 4); if (kx < guard) PUSHK(kx);
      kx = (pv.z & 0xFFFF0000u)  | (jq + 5); if (kx < guard) PUSHK(kx);
      kx = (pv.w << 16)          | (jq + 6); if (kx < guard) PUSHK(kx);
      kx = (pv.w & 0xFFFF0000u)  | (jq + 7); if (kx < guard) PUSHK(kx);
      if (__any(nc >= 4)) { DRAINALL; }
    }
    if (__any(nc > 0)) { DRAINALL; }

    // publish this half-row's 15th (upper bound on the row's 15th)
    if (td[14] < 0x7F000000u) atomicMin(&tauk[gi], td[14] + TAU_MARGIN);
    __syncthreads();
  }

  uint32* mdk = (uint32*)sm;
#pragma unroll
  for (int p = 0; p < 15; ++p) mdk[(myrow * 2 + h) * 15 + p] = td[p];
  __syncthreads();
  if (h == 0) {
    const uint32* la = &mdk[(myrow * 2 + 0) * 15];
    const uint32* lb = &mdk[(myrow * 2 + 1) * 15];
    int pa = 0, pb = 0;
    const size_t base = ((size_t)gi * NLIST + jsplit) * KNNK;
    for (int s = 0; s < KNNK; ++s) {
      const uint32 va = la[pa], vb = lb[pb];
      uint32 v;
      if (va <= vb) { v = va; ++pa; } else { v = vb; ++pb; }
      knnk[base + s] = v;
    }
  }
}

// ---------------------------------------------------------------- sig
// 240 keys (16 lists): radix-select rank-21 threshold (ballot+popc),
// ballot-prefix compaction, parallel coalesced refine, rank sort, gram,
// bitonic-128.
__global__ __launch_bounds__(256) void sig_kernel(
    const float* __restrict__ E, const uint32* __restrict__ knnk,
    const float* __restrict__ refc, const float* __restrict__ refa,
    float2* __restrict__ pacc) {
  __shared__ float gsm[4][352];  // gram 0..271 | inv 272..287 | cand 288..311
                                 // dsel 312..326 | nbr 328..342

  const int tid = threadIdx.x;
  const int wid = tid >> 6;
  const int L   = tid & 63;
  const int i   = blockIdx.x * 4 + wid;

  const uint32* kl = knnk + (size_t)i * NKEYS;   // 240 keys
  const uint32 k0 = kl[L];
  const uint32 k1 = kl[L + 64];
  const uint32 k2 = kl[L + 128];
  const uint32 k3 = (L < NKEYS - 192) ? kl[L + 192] : EMPTYK;  // 192..239

  // ---- radix-select the rank-(NCAND-1) key T (max T with count(<T)<=21)
  uint32 T = 0;
  for (int b = 31; b >= 0; --b) {
    const uint32 Tt = T | (1u << b);
    const int cnt = __popcll(__ballot(k0 < Tt)) + __popcll(__ballot(k1 < Tt)) +
                    __popcll(__ballot(k2 < Tt)) + __popcll(__ballot(k3 < Tt));
    if (cnt <= NCAND - 1) T = Tt;
  }

  // ---- compact the exactly-NCAND keys <= T into LDS via ballot-prefix
  uint32* candL = (uint32*)&gsm[wid][288];
  {
    const unsigned long long B0 = __ballot(k0 <= T);
    const unsigned long long B1 = __ballot(k1 <= T);
    const unsigned long long B2 = __ballot(k2 <= T);
    const unsigned long long B3 = __ballot(k3 <= T);
    int off = 0;
    if (k0 <= T) candL[off + lanes_below(B0)] = k0;
    off += __popcll(B0);
    if (k1 <= T) candL[off + lanes_below(B1)] = k1;
    off += __popcll(B1);
    if (k2 <= T) candL[off + lanes_below(B2)] = k2;
    off += __popcll(B2);
    if (k3 <= T) candL[off + lanes_below(B3)] = k3;
  }
  asm volatile("s_waitcnt lgkmcnt(0)" ::: "memory");
  const uint32 cand_key = (L < NCAND) ? candL[L] : EMPTYK;
  int cand_nb = ((cand_key >> 16) < 0x7F80u) ? (int)(cand_key & 0x1FFFu) : i;

  // ---- parallel exact refine: round r covers candidates r*8+g,
  //      group g = L>>3; lane u = L&7 reads float4s u+8t (coalesced).
  const float* Ei = E + (size_t)i * DIM;
  const int u = L & 7;
  const int g = L >> 3;
  float sr[3];
#pragma unroll
  for (int r = 0; r < 3; ++r) {
    const int c = r * 8 + g;                    // 0..23
    const int row = __shfl(cand_nb, c, 64);     // sentinel i for c>=22
    const float4* r4 = (const float4*)(E + (size_t)row * DIM);
    const float4* e4 = (const float4*)Ei;
    float a0 = 0.f, a1 = 0.f, a2 = 0.f, a3 = 0.f;
#pragma unroll
    for (int t = 0; t < 16; ++t) {
      const float4 av = r4[u + 8 * t];
      const float4 ev = e4[u + 8 * t];
      const float d0 = av.x - ev.x, d1 = av.y - ev.y;
      const float d2 = av.z - ev.z, d3 = av.w - ev.w;
      a0 = fmaf(d0, d0, a0); a1 = fmaf(d1, d1, a1);
      a2 = fmaf(d2, d2, a2); a3 = fmaf(d3, d3, a3);
    }
    float s = (a0 + a1) + (a2 + a3);
    s += __shfl_xor(s, 1, 64);
    s += __shfl_xor(s, 2, 64);
    s += __shfl_xor(s, 4, 64);
    sr[r] = s;
  }
  const int srcl = (L & 7) * 8;
  const float t0 = __shfl(sr[0], srcl, 64);
  const float t1 = __shfl(sr[1], srcl, 64);
  const float t2 = __shfl(sr[2], srcl, 64);
  float csq = (L >> 3) == 0 ? t0 : ((L >> 3) == 1 ? t1 : t2);
  if (L >= NCAND || cand_nb == i) csq = CINF;

  // ---- rank sort: NCAND independent readlane compares -> LDS rank slot
  int rank = 0;
#pragma unroll
  for (int j = 0; j < NCAND; ++j) {
    const float vj = __shfl(csq, j, 64);
    rank += (vj < csq) || (vj == csq && j < L);
  }
  float* dselL = &gsm[wid][312];
  int*   nbrL  = (int*)&gsm[wid][328];
  if (L < NCAND && rank < KNNK) { dselL[rank] = csq; nbrL[rank] = cand_nb; }
  asm volatile("s_waitcnt lgkmcnt(0)" ::: "memory");
  const int sel = L & 15;
  const int mynb = (sel < KNNK) ? nbrL[sel] : i;
  const float myd = (L < KNNK) ? sqrtf(fmaxf(dselL[L], 1e-12f)) : 0.f;

  // ---- curvature (lanes 0..14 hold ranks 0..14)
  float curvs;
  {
    float dd = (L < KNNK) ? myd : 0.f;
    float tot = wave_sum_f(dd);
    float mean_d = tot / (float)KNNK + 1e-8f;
    float diff = (L < KNNK) ? (dd / mean_d - refc[i * KNNK + L]) : 0.f;
    curvs = wave_sum_f(diff * diff);
  }

  // ---- gram of raw neighbor differences (row = L&15; row 15 = self -> zero)
  const float4* nb4 = (const float4*)(E + (size_t)mynb * DIM);
  const float4* ei4 = (const float4*)Ei;
  const int qo = (L >> 4) * 2;

  f32x4 gH, gX1, gX2;
#pragma unroll
  for (int r = 0; r < 4; ++r) { gH[r] = 0.f; gX1[r] = 0.f; gX2[r] = 0.f; }

#pragma unroll
  for (int c = 0; c < 16; ++c) {
    const float4 f0 = nb4[qo + c * 8];
    const float4 f1 = nb4[qo + 1 + c * 8];
    const float4 g0 = ei4[qo + c * 8];
    const float4 g1 = ei4[qo + 1 + c * 8];
    float v[8];
    v[0] = f0.x - g0.x; v[1] = f0.y - g0.y; v[2] = f0.z - g0.z; v[3] = f0.w - g0.w;
    v[4] = f1.x - g1.x; v[5] = f1.y - g1.y; v[6] = f1.z - g1.z; v[7] = f1.w - g1.w;
    short8 ah, al;
#pragma unroll
    for (int q = 0; q < 8; ++q) {
      short hh, ll;
      bf16split(v[q], hh, ll);
      ah[q] = hh; al[q] = ll;
    }
    gH  = __builtin_amdgcn_mfma_f32_16x16x32_bf16(ah, ah, gH, 0, 0, 0);
    gX1 = __builtin_amdgcn_mfma_f32_16x16x32_bf16(ah, al, gX1, 0, 0, 0);
    gX2 = __builtin_amdgcn_mfma_f32_16x16x32_bf16(al, ah, gX2, 0, 0, 0);
  }

#pragma unroll
  for (int q = 0; q < 4; ++q)
    gsm[wid][((L >> 4) * 4 + q) * 17 + (L & 15)] = gH[q] + gX1[q] + gX2[q];
  asm volatile("s_waitcnt lgkmcnt(0)" ::: "memory");

  if (L < 16) {
    const float dv = gsm[wid][L * 17 + L];
    const float nrm = sqrtf(fmaxf(dv, 0.f));
    gsm[wid][272 + L] = 1.0f / fmaxf(nrm, 1e-8f);
  }
  asm volatile("s_waitcnt lgkmcnt(0)" ::: "memory");

  float c0 = CINF, c1 = CINF;
#pragma unroll
  for (int s = 0; s < 2; ++s) {
    const int p = L + 64 * s;
    if (p < NPAIR) {
      int a = 0, rem = p, cnt = 14;
      while (rem >= cnt) { rem -= cnt; --cnt; ++a; }
      const int b = a + 1 + rem;
      const float cv = gsm[wid][a * 17 + b] * gsm[wid][272 + a] * gsm[wid][272 + b];
      if (s == 0) c0 = cv; else c1 = cv;
    }
  }

  // bitonic-128 ascending
#pragma unroll
  for (int k = 2; k <= 128; k <<= 1) {
#pragma unroll
    for (int j = k >> 1; j >= 1; j >>= 1) {
      const bool dir = ((L & (k >> 1)) == 0);
      if (j == 1) {
        const float lo = fminf(c0, c1), hi = fmaxf(c0, c1);
        c0 = dir ? lo : hi;
        c1 = dir ? hi : lo;
      } else {
        const int m = j >> 1;
        const float o0 = __shfl_xor(c0, m, 64);
        const float o1 = __shfl_xor(c1, m, 64);
        const bool lower = ((L & m) == 0);
        c0 = (lower == dir) ? fminf(c0, o0) : fmaxf(c0, o0);
        c1 = (lower == dir) ? fminf(c1, o1) : fmaxf(c1, o1);
      }
    }
  }

  float part = 0.f;
  {
    const int r0 = 2 * L, r1 = 2 * L + 1;
    if (r0 < NPAIR) { const float dd = c0 - refa[(size_t)i * NPAIR + r0]; part += dd * dd; }
    if (r1 < NPAIR) { const float dd = c1 - refa[(size_t)i * NPAIR + r1]; part += dd * dd; }
  }
  part = wave_sum_f(part);
  if (L == 0) pacc[i] = make_float2(curvs, part);
}

// ---------------------------------------------------------------- fin
__global__ __launch_bounds__(256) void fin_kernel(
    const float2* __restrict__ pacc, float* __restrict__ out) {
  __shared__ double redc[4], reda[4];
  const int tid = threadIdx.x;
  const int wid = tid >> 6;
  const int L   = tid & 63;
  double sc = 0.0, sa = 0.0;
#pragma unroll
  for (int q = 0; q < 32; ++q) {
    const float2 p = pacc[tid + 256 * q];
    sc += (double)p.x;
    sa += (double)p.y;
  }
#pragma unroll
  for (int m = 32; m > 0; m >>= 1) {
    sc += __shfl_xor(sc, m, 64);
    sa += __shfl_xor(sa, m, 64);
  }
  if (L == 0) { redc[wid] = sc; reda[wid] = sa; }
  __syncthreads();
  if (tid == 0) {
    const double curv = (redc[0] + redc[1] + redc[2] + redc[3]) /
                        ((double)NPTS * (double)KNNK);
    const double ang  = (reda[0] + reda[1] + reda[2] + reda[3]) /
                        ((double)NPTS * (double)NPAIR);
    out[0] = (float)(0.3 * curv + 0.7 * ang);
  }
}

// ---------------------------------------------------------------- launch
extern "C" void kernel_launch(void* const* d_in, const int* in_sizes, int n_in,
                              void* d_out, int out_size, void* d_ws,
                              size_t ws_size, hipStream_t stream) {
  const float* E    = (const float*)d_in[0];
  const float* refc = (const float*)d_in[1];
  const float* refa = (const float*)d_in[2];
  float* out = (float*)d_out;

  char* ws = (char*)d_ws;
  float*  sqn  = (float*)(ws + 1024);
  float2* pacc = (float2*)(ws + 65536);
  uint32* tauk = (uint32*)(ws + 131072);      // [NPTS]
  ushort* EA   = (ushort*)(ws + 1048576);
  ushort* EB   = (ushort*)(ws + 9437184);
  uint32* knnk = (uint32*)(ws + 17825792);    // [NPTS][16][15] keys (7.9 MB)

  prep_kernel<<<NPTS / 4, 256, 0, stream>>>(E, sqn, EA, EB, tauk);
  knn_kernel<<<dim3(NPTS / NI, NJSPLIT), 256, 0, stream>>>(EA, EB, sqn, tauk, knnk);
  sig_kernel<<<NPTS / 4, 256, 0, stream>>>(E, knnk, refc, refa, pacc);
  fin_kernel<<<1, 256, 0, stream>>>(pacc, out);
}

// Round 14
// 260.530 us; speedup vs baseline: 1.1134x; 1.0665x over previous
//
#include <hip/hip_runtime.h>
#include <hip/hip_bf16.h>
#include <math.h>

#define NPTS  8192
#define DIM   512
#define KNNK  15
#define NCAND 24
#define NPAIR 105
#define CINF  3.0e38f
#define EMPTYK 0xFFFFFFFFu
#define TAU_MARGIN (6u << 16)   // +6 bf16 ulp (covers i8 screen err, ~8 sigma)

// knn tiling: one split (128 x 512) per block; grid 64x16 = 1024 = 4/CU
#define NI      128
#define NJSPLIT 16
#define NJ      (NPTS/NJSPLIT)   // 512
#define JS      128
#define NSUB    (NJ/JS)          // 4
#define BKB     64               // chunk K-depth in i8 elems (bytes)
#define NCH     (DIM/BKB)        // 8 chunks, double-buffered
#define SDW     68               // packed sdist row stride in dwords
#define NLIST   NJSPLIT          // 16 lists per point
#define NKEYS   (NLIST * KNNK)   // 240 keys per point

// knn LDS byte map (39936 B -> 4 blocks/CU):
//   buf = A[128][64B] (8KB) + B[128][64B] (8KB); double-buffered at 0/16384
#define BUF0_OFF   0
#define BUF1_OFF   16384
#define SQJ_OFF    34816
#define KNN_LDS    39936

typedef __attribute__((ext_vector_type(4))) int i32x4;
typedef unsigned int uint32;

static __device__ __forceinline__ float wave_sum_f(float v) {
#pragma unroll
  for (int m = 32; m > 0; m >>= 1) v += __shfl_xor(v, m, 64);
  return v;
}

static __device__ __forceinline__ void load_lds16(const void* g, void* l) {
  __builtin_amdgcn_global_load_lds(
      (const __attribute__((address_space(1))) void*)g,
      (__attribute__((address_space(3))) void*)l, 16, 0, 0);
}

static __device__ __forceinline__ void bf16split(float x, short& h, short& l) {
  __hip_bfloat16 hb = __float2bfloat16(x);
  const float hf = __bfloat162float(hb);
  __hip_bfloat16 lb = __float2bfloat16(x - hf);
  h = *(short*)&hb;
  l = *(short*)&lb;
}

// # of set bits of B strictly below this lane
static __device__ __forceinline__ int lanes_below(unsigned long long B) {
  int c = __builtin_amdgcn_mbcnt_lo((uint32)B, 0);
  return __builtin_amdgcn_mbcnt_hi((uint32)(B >> 32), c);
}

// sorted-ascending insert of key c into td[0..14]
static __device__ __forceinline__ void chain15(uint32 (&td)[15], uint32 c) {
#pragma unroll
  for (int p = 0; p < 15; ++p) {
    const uint32 lo = min(c, td[p]);
    const uint32 hi = max(c, td[p]);
    td[p] = lo; c = hi;
  }
}

#define PUSHK(k_) { const uint32 kv_ = (k_); \
  p0=(nc==0)?kv_:p0;  p1=(nc==1)?kv_:p1;  p2=(nc==2)?kv_:p2; \
  p3=(nc==3)?kv_:p3;  p4=(nc==4)?kv_:p4;  p5=(nc==5)?kv_:p5; \
  p6=(nc==6)?kv_:p6;  p7=(nc==7)?kv_:p7;  p8=(nc==8)?kv_:p8; \
  p9=(nc==9)?kv_:p9;  p10=(nc==10)?kv_:p10; p11=(nc==11)?kv_:p11; \
  ++nc; }

#define DRAINALL { \
  if (__any(nc >  0)) { if (nc >  0) chain15(td, p0);  } \
  if (__any(nc >  1)) { if (nc >  1) chain15(td, p1);  } \
  if (__any(nc >  2)) { if (nc >  2) chain15(td, p2);  } \
  if (__any(nc >  3)) { if (nc >  3) chain15(td, p3);  } \
  if (__any(nc >  4)) { if (nc >  4) chain15(td, p4);  } \
  if (__any(nc >  5)) { if (nc >  5) chain15(td, p5);  } \
  if (__any(nc >  6)) { if (nc >  6) chain15(td, p6);  } \
  if (__any(nc >  7)) { if (nc >  7) chain15(td, p7);  } \
  if (__any(nc >  8)) { if (nc >  8) chain15(td, p8);  } \
  if (__any(nc >  9)) { if (nc >  9) chain15(td, p9);  } \
  if (__any(nc > 10)) { if (nc > 10) chain15(td, p10); } \
  if (__any(nc > 11)) { if (nc > 11) chain15(td, p11); } \
  nc = 0; guard = min(tau_cur, td[14]); }

// ---------------------------------------------------------------- prep
// Quantize to i8 scale 32 (clip 3.97 sigma): EA = Q(-x), EB = Q(x).
// sqnh = (sum Q(x)^2) >> 1 so screen acc = sqnh_j - S^2*xy directly
// (row-constant -S^2*sqn_i/2 offset is ranking-invariant).
__global__ __launch_bounds__(256) void prep_kernel(
    const float* __restrict__ E, int* __restrict__ sqnh,
    unsigned char* __restrict__ EA, unsigned char* __restrict__ EB,
    uint32* __restrict__ tauk) {
  const int row  = blockIdx.x * 4 + (threadIdx.x >> 6);
  const int lane = threadIdx.x & 63;
  const float4* e4 = (const float4*)(E + (size_t)row * DIM);
  const float4 f0 = e4[lane * 2];
  const float4 f1 = e4[lane * 2 + 1];
  const float xs[8] = {f0.x, f0.y, f0.z, f0.w, f1.x, f1.y, f1.z, f1.w};
  int ss = 0;
  uint32 pa0 = 0, pa1 = 0, pb0 = 0, pb1 = 0;
#pragma unroll
  for (int t = 0; t < 8; ++t) {
    const float v = fminf(fmaxf(xs[t] * 32.0f, -127.0f), 127.0f);
    const int q = __float2int_rn(v);
    ss += q * q;
    const uint32 ub = (uint32)(q & 0xFF);
    const uint32 ua = (uint32)((-q) & 0xFF);
    if (t < 4) { pb0 |= ub << (8 * t);       pa0 |= ua << (8 * t); }
    else       { pb1 |= ub << (8 * (t - 4)); pa1 |= ua << (8 * (t - 4)); }
  }
  uint2 wa; wa.x = pa0; wa.y = pa1;
  uint2 wb; wb.x = pb0; wb.y = pb1;
  ((uint2*)(EA + (size_t)row * DIM))[lane] = wa;
  ((uint2*)(EB + (size_t)row * DIM))[lane] = wb;
#pragma unroll
  for (int m = 32; m > 0; m >>= 1) ss += __shfl_xor(ss, m, 64);
  if (lane == 0) { sqnh[row] = ss >> 1; tauk[row] = EMPTYK; }
}

// ---------------------------------------------------------------- knn
// FUSED i8 screen (K=64 MFMA at 2x bf16 rate, half the chunks/barriers/
// frag-reads/staging). tau: device-global monotone bound via atomicMin,
// read fresh per subtile (stale = weaker guard, still correct).
__global__ __launch_bounds__(256, 4) void knn_kernel(
    const unsigned char* __restrict__ EA, const unsigned char* __restrict__ EB,
    const int* __restrict__ sqnh, uint32* __restrict__ tauk,
    uint32* __restrict__ knnk) {
  __shared__ __align__(16) char sm[KNN_LDS];
  uint32* sdp  = (uint32*)sm;
  int*    sqji = (int*)(sm + SQJ_OFF);

  const int tid = threadIdx.x;
  const int w   = tid >> 6;
  const int L   = tid & 63;
  const int wr  = (w >> 1) & 1;
  const int wc  = w & 1;
  const int i0  = blockIdx.x * NI;
  const int jsplit = blockIdx.y;
  const int j0  = jsplit * NJ;

  if (tid < NJ / 4) ((int4*)sqji)[tid] = ((const int4*)(sqnh + j0))[tid];

  const unsigned char* gsrc = (w < 2) ? EA : EB;
  const int lrow   = L >> 2;                               // 0..15
  const int swz_kB = ((L & 3) ^ ((L >> 3) & 3)) * 16;      // pre-swz, bytes
  const int lds_woff = ((w < 2) ? 0 : 8192) + (w & 1) * 4096;
  const int slotB  = (((L >> 4) ^ ((L >> 1) & 3)) * 16);   // same involution

  const int myrow = tid >> 1;
  const int h     = tid & 1;
  const int gi    = i0 + myrow;

  uint32 td[15];
#pragma unroll
  for (int p = 0; p < 15; ++p) td[p] = EMPTYK;

  __syncthreads();

  for (int js = 0; js < NSUB; ++js) {
    const int jrow0 = j0 + js * JS;
    const int trowW = ((w < 2) ? i0 : jrow0) + (w & 1) * 64;
    const unsigned char* gbase = gsrc + (size_t)(trowW + lrow) * DIM + swz_kB;

    // acc init = sqnh_j along the r (reg) dim
    i32x4 acc[4][4];
#pragma unroll
    for (int fj = 0; fj < 4; ++fj) {
      const i32x4 sq = *(const i32x4*)&sqji[js * 128 + wc * 64 + fj * 16 + (L >> 4) * 4];
#pragma unroll
      for (int fi = 0; fi < 4; ++fi) acc[fj][fi] = sq;
    }

    // prologue: stage chunk 0 into buf0 (4 x 16B per thread)
    {
      char* lp = sm + BUF0_OFF + lds_woff;
#pragma unroll
      for (int s = 0; s < 4; ++s)
        load_lds16(gbase + (size_t)(s * 16) * DIM, lp + s * 1024);
    }
    __syncthreads();

#pragma unroll 2
    for (int ch = 0; ch < NCH; ++ch) {
      const int cb  = (ch & 1) ? BUF1_OFF : BUF0_OFF;
      const int nbo = (ch & 1) ? BUF0_OFF : BUF1_OFF;
      if (ch < NCH - 1) {
        char* lp = sm + nbo + lds_woff;
        const unsigned char* gp = gbase + (ch + 1) * BKB;
#pragma unroll
        for (int s = 0; s < 4; ++s)
          load_lds16(gp + (size_t)(s * 16) * DIM, lp + s * 1024);
      }

      const char* sA = (const char*)(sm + cb);          // [128][64B]
      const char* sB = (const char*)(sm + cb + 8192);   // [128][64B]

      i32x4 a[4], b[4];
#pragma unroll
      for (int f = 0; f < 4; ++f) {
        a[f] = *(const i32x4*)&sA[(wr * 64 + f * 16 + (L & 15)) * BKB + slotB];
        b[f] = *(const i32x4*)&sB[(wc * 64 + f * 16 + (L & 15)) * BKB + slotB];
      }
      // swapped operands: reg dim = j (b), lane dim = i (a)
#pragma unroll
      for (int fj = 0; fj < 4; ++fj)
#pragma unroll
        for (int fi = 0; fi < 4; ++fi)
          acc[fj][fi] = __builtin_amdgcn_mfma_i32_16x16x64_i8(b[fj], a[fi], acc[fj][fi], 0, 0, 0);
      __syncthreads();   // drains next-chunk staging; orders buffer reuse
    }

    // ---- writeback: i32 -> f32 -> packed bf16, one b64 store per frag
#pragma unroll
    for (int fj = 0; fj < 4; ++fj)
#pragma unroll
      for (int fi = 0; fi < 4; ++fi) {
        const int i_t = wr * 64 + fi * 16 + (L & 15);
        const int jd  = wc * 32 + fj * 8 + (L >> 4) * 2;
        const float v0 = (float)acc[fj][fi][0];
        const float v1 = (float)acc[fj][fi][1];
        const float v2 = (float)acc[fj][fi][2];
        const float v3 = (float)acc[fj][fi][3];
        uint32 dw0, dw1;
        asm("v_cvt_pk_bf16_f32 %0, %1, %2" : "=v"(dw0) : "v"(v0), "v"(v1));
        asm("v_cvt_pk_bf16_f32 %0, %1, %2" : "=v"(dw1) : "v"(v2), "v"(v3));
        uint2 d2; d2.x = dw0; d2.y = dw1;
        *(uint2*)&sdp[i_t * SDW + jd] = d2;
      }
    __syncthreads();

    // fresh monotone tau (stale value = weaker guard, still correct)
    const uint32 tau_cur = __hip_atomic_load(&tauk[gi], __ATOMIC_RELAXED,
                                             __HIP_MEMORY_SCOPE_AGENT);
    const int selfc = gi - jrow0;
    if (selfc >= 0 && selfc < JS && h == (selfc >> 6))
      *(ushort*)(sm + myrow * (SDW * 4) + selfc * 2) = 0x7F80;   // bf16 +inf

    const uint32* rowp = sdp + myrow * SDW + 32 * h;
    const uint32 jb = (uint32)(jrow0 + 64 * h);
    uint32 guard = min(tau_cur, td[14]);
    uint32 nc = 0;
    uint32 p0=0,p1=0,p2=0,p3=0,p4=0,p5=0,p6=0,p7=0,p8=0,p9=0,p10=0,p11=0;

#pragma unroll 2
    for (int q = 0; q < 8; ++q) {
      const uint4 pv = *(const uint4*)&rowp[4 * q];
      const uint32 jq = jb + 8 * q;
      uint32 kx;
      kx = (pv.x << 16)          | (jq + 0); if (kx < guard) PUSHK(kx);
      kx = (pv.x & 0xFFFF0000u)  | (jq + 1); if (kx < guard) PUSHK(kx);
      kx = (pv.y << 16)          | (jq + 2); if (kx < guard) PUSHK(kx);
      kx = (pv.y & 0xFFFF0000u)  | (jq + 3); if (kx < guard) PUSHK(kx);
      kx = (pv.z << 16)          | (jq + 4); if (kx < guard) PUSHK(kx);
      kx = (pv.z & 0xFFFF0000u)  | (jq + 5); if (kx < guard) PUSHK(kx);
      kx = (pv.w << 16)          | (jq + 6); if (kx < guard) PUSHK(kx);
      kx = (pv.w & 0xFFFF0000u)  | (jq + 7); if (kx < guard) PUSHK(kx);
      if (__any(nc >= 4)) { DRAINALL; }
    }
    if (__any(nc > 0)) { DRAINALL; }

    // publish this half-row's 15th (upper bound on the row's 15th)
    if (td[14] < 0x7F000000u) atomicMin(&tauk[gi], td[14] + TAU_MARGIN);
    __syncthreads();
  }

  uint32* mdk = (uint32*)sm;
#pragma unroll
  for (int p = 0; p < 15; ++p) mdk[(myrow * 2 + h) * 15 + p] = td[p];
  __syncthreads();
  if (h == 0) {
    const uint32* la = &mdk[(myrow * 2 + 0) * 15];
    const uint32* lb = &mdk[(myrow * 2 + 1) * 15];
    int pa = 0, pb = 0;
    const size_t base = ((size_t)gi * NLIST + jsplit) * KNNK;
    for (int s = 0; s < KNNK; ++s) {
      const uint32 va = la[pa], vb = lb[pb];
      uint32 v;
      if (va <= vb) { v = va; ++pa; } else { v = vb; ++pb; }
      knnk[base + s] = v;
    }
  }
}

// ---------------------------------------------------------------- sig
// 240 keys (16 lists): radix-select rank-23 threshold (ballot+popc),
// ballot-prefix compaction (24 cands), parallel coalesced refine (3x8),
// rank sort, gram, bitonic-128.
__global__ __launch_bounds__(256) void sig_kernel(
    const float* __restrict__ E, const uint32* __restrict__ knnk,
    const float* __restrict__ refc, const float* __restrict__ refa,
    float2* __restrict__ pacc) {
  __shared__ float gsm[4][352];  // gram 0..271 | inv 272..287 | cand 288..311
                                 // dsel 312..326 | nbr 328..342

  const int tid = threadIdx.x;
  const int wid = tid >> 6;
  const int L   = tid & 63;
  const int i   = blockIdx.x * 4 + wid;

  const uint32* kl = knnk + (size_t)i * NKEYS;   // 240 keys
  const uint32 k0 = kl[L];
  const uint32 k1 = kl[L + 64];
  const uint32 k2 = kl[L + 128];
  const uint32 k3 = (L < NKEYS - 192) ? kl[L + 192] : EMPTYK;  // 192..239

  // ---- radix-select the rank-(NCAND-1) key T (max T with count(<T)<=23)
  uint32 T = 0;
  for (int b = 31; b >= 0; --b) {
    const uint32 Tt = T | (1u << b);
    const int cnt = __popcll(__ballot(k0 < Tt)) + __popcll(__ballot(k1 < Tt)) +
                    __popcll(__ballot(k2 < Tt)) + __popcll(__ballot(k3 < Tt));
    if (cnt <= NCAND - 1) T = Tt;
  }

  // ---- compact the exactly-NCAND keys <= T into LDS via ballot-prefix
  uint32* candL = (uint32*)&gsm[wid][288];
  {
    const unsigned long long B0 = __ballot(k0 <= T);
    const unsigned long long B1 = __ballot(k1 <= T);
    const unsigned long long B2 = __ballot(k2 <= T);
    const unsigned long long B3 = __ballot(k3 <= T);
    int off = 0;
    if (k0 <= T) candL[off + lanes_below(B0)] = k0;
    off += __popcll(B0);
    if (k1 <= T) candL[off + lanes_below(B1)] = k1;
    off += __popcll(B1);
    if (k2 <= T) candL[off + lanes_below(B2)] = k2;
    off += __popcll(B2);
    if (k3 <= T) candL[off + lanes_below(B3)] = k3;
  }
  asm volatile("s_waitcnt lgkmcnt(0)" ::: "memory");
  const uint32 cand_key = (L < NCAND) ? candL[L] : EMPTYK;
  int cand_nb = ((cand_key >> 16) < 0x7F80u) ? (int)(cand_key & 0x1FFFu) : i;

  // ---- parallel exact refine: round r covers candidates r*8+g,
  //      group g = L>>3; lane u = L&7 reads float4s u+8t (coalesced).
  const float* Ei = E + (size_t)i * DIM;
  const int u = L & 7;
  const int g = L >> 3;
  float sr[3];
#pragma unroll
  for (int r = 0; r < 3; ++r) {
    const int c = r * 8 + g;                    // 0..23
    const int row = __shfl(cand_nb, c, 64);
    const float4* r4 = (const float4*)(E + (size_t)row * DIM);
    const float4* e4 = (const float4*)Ei;
    float a0 = 0.f, a1 = 0.f, a2 = 0.f, a3 = 0.f;
#pragma unroll
    for (int t = 0; t < 16; ++t) {
      const float4 av = r4[u + 8 * t];
      const float4 ev = e4[u + 8 * t];
      const float d0 = av.x - ev.x, d1 = av.y - ev.y;
      const float d2 = av.z - ev.z, d3 = av.w - ev.w;
      a0 = fmaf(d0, d0, a0); a1 = fmaf(d1, d1, a1);
      a2 = fmaf(d2, d2, a2); a3 = fmaf(d3, d3, a3);
    }
    float s = (a0 + a1) + (a2 + a3);
    s += __shfl_xor(s, 1, 64);
    s += __shfl_xor(s, 2, 64);
    s += __shfl_xor(s, 4, 64);
    sr[r] = s;
  }
  const int srcl = (L & 7) * 8;
  const float t0 = __shfl(sr[0], srcl, 64);
  const float t1 = __shfl(sr[1], srcl, 64);
  const float t2 = __shfl(sr[2], srcl, 64);
  float csq = (L >> 3) == 0 ? t0 : ((L >> 3) == 1 ? t1 : t2);
  if (L >= NCAND || cand_nb == i) csq = CINF;

  // ---- rank sort: NCAND independent readlane compares -> LDS rank slot
  int rank = 0;
#pragma unroll
  for (int j = 0; j < NCAND; ++j) {
    const float vj = __shfl(csq, j, 64);
    rank += (vj < csq) || (vj == csq && j < L);
  }
  float* dselL = &gsm[wid][312];
  int*   nbrL  = (int*)&gsm[wid][328];
  if (L < NCAND && rank < KNNK) { dselL[rank] = csq; nbrL[rank] = cand_nb; }
  asm volatile("s_waitcnt lgkmcnt(0)" ::: "memory");
  const int sel = L & 15;
  const int mynb = (sel < KNNK) ? nbrL[sel] : i;
  const float myd = (L < KNNK) ? sqrtf(fmaxf(dselL[L], 1e-12f)) : 0.f;

  // ---- curvature (lanes 0..14 hold ranks 0..14)
  float curvs;
  {
    float dd = (L < KNNK) ? myd : 0.f;
    float tot = wave_sum_f(dd);
    float mean_d = tot / (float)KNNK + 1e-8f;
    float diff = (L < KNNK) ? (dd / mean_d - refc[i * KNNK + L]) : 0.f;
    curvs = wave_sum_f(diff * diff);
  }

  // ---- gram of raw neighbor differences (row = L&15; row 15 = self -> zero)
  const float4* nb4 = (const float4*)(E + (size_t)mynb * DIM);
  const float4* ei4 = (const float4*)Ei;
  const int qo = (L >> 4) * 2;

  typedef __attribute__((ext_vector_type(8))) short short8;
  typedef __attribute__((ext_vector_type(4))) float f32x4;
  f32x4 gH, gX1, gX2;
#pragma unroll
  for (int r = 0; r < 4; ++r) { gH[r] = 0.f; gX1[r] = 0.f; gX2[r] = 0.f; }

#pragma unroll
  for (int c = 0; c < 16; ++c) {
    const float4 f0 = nb4[qo + c * 8];
    const float4 f1 = nb4[qo + 1 + c * 8];
    const float4 g0 = ei4[qo + c * 8];
    const float4 g1 = ei4[qo + 1 + c * 8];
    float v[8];
    v[0] = f0.x - g0.x; v[1] = f0.y - g0.y; v[2] = f0.z - g0.z; v[3] = f0.w - g0.w;
    v[4] = f1.x - g1.x; v[5] = f1.y - g1.y; v[6] = f1.z - g1.z; v[7] = f1.w - g1.w;
    short8 ah, al;
#pragma unroll
    for (int q = 0; q < 8; ++q) {
      short hh, ll;
      bf16split(v[q], hh, ll);
      ah[q] = hh; al[q] = ll;
    }
    gH  = __builtin_amdgcn_mfma_f32_16x16x32_bf16(ah, ah, gH, 0, 0, 0);
    gX1 = __builtin_amdgcn_mfma_f32_16x16x32_bf16(ah, al, gX1, 0, 0, 0);
    gX2 = __builtin_amdgcn_mfma_f32_16x16x32_bf16(al, ah, gX2, 0, 0, 0);
  }

#pragma unroll
  for (int q = 0; q < 4; ++q)
    gsm[wid][((L >> 4) * 4 + q) * 17 + (L & 15)] = gH[q] + gX1[q] + gX2[q];
  asm volatile("s_waitcnt lgkmcnt(0)" ::: "memory");

  if (L < 16) {
    const float dv = gsm[wid][L * 17 + L];
    const float nrm = sqrtf(fmaxf(dv, 0.f));
    gsm[wid][272 + L] = 1.0f / fmaxf(nrm, 1e-8f);
  }
  asm volatile("s_waitcnt lgkmcnt(0)" ::: "memory");

  float c0 = CINF, c1 = CINF;
#pragma unroll
  for (int s = 0; s < 2; ++s) {
    const int p = L + 64 * s;
    if (p < NPAIR) {
      int a = 0, rem = p, cnt = 14;
      while (rem >= cnt) { rem -= cnt; --cnt; ++a; }
      const int b = a + 1 + rem;
      const float cv = gsm[wid][a * 17 + b] * gsm[wid][272 + a] * gsm[wid][272 + b];
      if (s == 0) c0 = cv; else c1 = cv;
    }
  }

  // bitonic-128 ascending
#pragma unroll
  for (int k = 2; k <= 128; k <<= 1) {
#pragma unroll
    for (int j = k >> 1; j >= 1; j >>= 1) {
      const bool dir = ((L & (k >> 1)) == 0);
      if (j == 1) {
        const float lo = fminf(c0, c1), hi = fmaxf(c0, c1);
        c0 = dir ? lo : hi;
        c1 = dir ? hi : lo;
      } else {
        const int m = j >> 1;
        const float o0 = __shfl_xor(c0, m, 64);
        const float o1 = __shfl_xor(c1, m, 64);
        const bool lower = ((L & m) == 0);
        c0 = (lower == dir) ? fminf(c0, o0) : fmaxf(c0, o0);
        c1 = (lower == dir) ? fminf(c1, o1) : fmaxf(c1, o1);
      }
    }
  }

  float part = 0.f;
  {
    const int r0 = 2 * L, r1 = 2 * L + 1;
    if (r0 < NPAIR) { const float dd = c0 - refa[(size_t)i * NPAIR + r0]; part += dd * dd; }
    if (r1 < NPAIR) { const float dd = c1 - refa[(size_t)i * NPAIR + r1]; part += dd * dd; }
  }
  part = wave_sum_f(part);
  if (L == 0) pacc[i] = make_float2(curvs, part);
}

// ---------------------------------------------------------------- fin
__global__ __launch_bounds__(256) void fin_kernel(
    const float2* __restrict__ pacc, float* __restrict__ out) {
  __shared__ double redc[4], reda[4];
  const int tid = threadIdx.x;
  const int wid = tid >> 6;
  const int L   = tid & 63;
  double sc = 0.0, sa = 0.0;
#pragma unroll
  for (int q = 0; q < 32; ++q) {
    const float2 p = pacc[tid + 256 * q];
    sc += (double)p.x;
    sa += (double)p.y;
  }
#pragma unroll
  for (int m = 32; m > 0; m >>= 1) {
    sc += __shfl_xor(sc, m, 64);
    sa += __shfl_xor(sa, m, 64);
  }
  if (L == 0) { redc[wid] = sc; reda[wid] = sa; }
  __syncthreads();
  if (tid == 0) {
    const double curv = (redc[0] + redc[1] + redc[2] + redc[3]) /
                        ((double)NPTS * (double)KNNK);
    const double ang  = (reda[0] + reda[1] + reda[2] + reda[3]) /
                        ((double)NPTS * (double)NPAIR);
    out[0] = (float)(0.3 * curv + 0.7 * ang);
  }
}

// ---------------------------------------------------------------- launch
extern "C" void kernel_launch(void* const* d_in, const int* in_sizes, int n_in,
                              void* d_out, int out_size, void* d_ws,
                              size_t ws_size, hipStream_t stream) {
  const float* E    = (const float*)d_in[0];
  const float* refc = (const float*)d_in[1];
  const float* refa = (const float*)d_in[2];
  float* out = (float*)d_out;

  char* ws = (char*)d_ws;
  int*    sqnh = (int*)(ws + 1024);
  float2* pacc = (float2*)(ws + 65536);
  uint32* tauk = (uint32*)(ws + 131072);      // [NPTS]
  unsigned char* EA = (unsigned char*)(ws + 1048576);   // 4 MB
  unsigned char* EB = (unsigned char*)(ws + 9437184);   // 4 MB
  uint32* knnk = (uint32*)(ws + 17825792);    // [NPTS][16][15] keys (7.9 MB)

  prep_kernel<<<NPTS / 4, 256, 0, stream>>>(E, sqnh, EA, EB, tauk);
  knn_kernel<<<dim3(NPTS / NI, NJSPLIT), 256, 0, stream>>>(EA, EB, sqnh, tauk, knnk);
  sig_kernel<<<NPTS / 4, 256, 0, stream>>>(E, knnk, refc, refa, pacc);
  fin_kernel<<<1, 256, 0, stream>>>(pacc, out);
}

// Round 15
// 257.240 us; speedup vs baseline: 1.1277x; 1.0128x over previous
//
#include <hip/hip_runtime.h>
#include <hip/hip_bf16.h>
#include <math.h>

#define NPTS  8192
#define DIM   512
#define KNNK  15
#define NCAND 24
#define NPAIR 105
#define CINF  3.0e38f
#define EMPTYK 0xFFFFFFFFu
#define TAU_MARGIN (6u << 16)   // +6 bf16 ulp (covers i8 screen err, ~8 sigma)

// knn tiling: one split (128 x 512) per block; grid 64x16 = 1024 = 4/CU
#define NI      128
#define NJSPLIT 16
#define NJ      (NPTS/NJSPLIT)   // 512
#define JS      128
#define NSUB    (NJ/JS)          // 4
#define BKB     64               // chunk K-depth in i8 elems (bytes)
#define NCH     (DIM/BKB)        // 8 chunks, double-buffered
#define SDW     68               // packed sdist row stride in dwords
#define NLIST   NJSPLIT          // 16 lists per point
#define NKEYS   (NLIST * KNNK)   // 240 keys per point

// knn LDS byte map (39936 B -> 4 blocks/CU):
//   buf = A[128][64B] (8KB) + B[128][64B] (8KB); double-buffered at 0/16384
#define BUF0_OFF   0
#define BUF1_OFF   16384
#define SQJ_OFF    34816
#define KNN_LDS    39936

typedef __attribute__((ext_vector_type(4))) int i32x4;
typedef unsigned int uint32;

static __device__ __forceinline__ float wave_sum_f(float v) {
#pragma unroll
  for (int m = 32; m > 0; m >>= 1) v += __shfl_xor(v, m, 64);
  return v;
}

static __device__ __forceinline__ void load_lds16(const void* g, void* l) {
  __builtin_amdgcn_global_load_lds(
      (const __attribute__((address_space(1))) void*)g,
      (__attribute__((address_space(3))) void*)l, 16, 0, 0);
}

// truncation split: h = top-16-bit mask of x (exact), l = bf16(x - h).
// Same h+l error structure as round-split; fewer VALU ops.
static __device__ __forceinline__ void bf16split(float x, short& h, short& l) {
  const uint32 xb = __float_as_uint(x);
  const uint32 hb = xb & 0xFFFF0000u;
  h = (short)(hb >> 16);
  const float lf = x - __uint_as_float(hb);
  __hip_bfloat16 lb = __float2bfloat16(lf);
  l = *(short*)&lb;
}

// # of set bits of B strictly below this lane
static __device__ __forceinline__ int lanes_below(unsigned long long B) {
  int c = __builtin_amdgcn_mbcnt_lo((uint32)B, 0);
  return __builtin_amdgcn_mbcnt_hi((uint32)(B >> 32), c);
}

// sorted-ascending insert of key c into td[0..14]
static __device__ __forceinline__ void chain15(uint32 (&td)[15], uint32 c) {
#pragma unroll
  for (int p = 0; p < 15; ++p) {
    const uint32 lo = min(c, td[p]);
    const uint32 hi = max(c, td[p]);
    td[p] = lo; c = hi;
  }
}

#define PUSHK(k_) { const uint32 kv_ = (k_); \
  p0=(nc==0)?kv_:p0;  p1=(nc==1)?kv_:p1;  p2=(nc==2)?kv_:p2; \
  p3=(nc==3)?kv_:p3;  p4=(nc==4)?kv_:p4;  p5=(nc==5)?kv_:p5; \
  p6=(nc==6)?kv_:p6;  p7=(nc==7)?kv_:p7;  p8=(nc==8)?kv_:p8; \
  p9=(nc==9)?kv_:p9;  p10=(nc==10)?kv_:p10; p11=(nc==11)?kv_:p11; \
  ++nc; }

#define DRAINALL { \
  if (__any(nc >  0)) { if (nc >  0) chain15(td, p0);  } \
  if (__any(nc >  1)) { if (nc >  1) chain15(td, p1);  } \
  if (__any(nc >  2)) { if (nc >  2) chain15(td, p2);  } \
  if (__any(nc >  3)) { if (nc >  3) chain15(td, p3);  } \
  if (__any(nc >  4)) { if (nc >  4) chain15(td, p4);  } \
  if (__any(nc >  5)) { if (nc >  5) chain15(td, p5);  } \
  if (__any(nc >  6)) { if (nc >  6) chain15(td, p6);  } \
  if (__any(nc >  7)) { if (nc >  7) chain15(td, p7);  } \
  if (__any(nc >  8)) { if (nc >  8) chain15(td, p8);  } \
  if (__any(nc >  9)) { if (nc >  9) chain15(td, p9);  } \
  if (__any(nc > 10)) { if (nc > 10) chain15(td, p10); } \
  if (__any(nc > 11)) { if (nc > 11) chain15(td, p11); } \
  nc = 0; guard = min(tau_cur, td[14]); }

// ---------------------------------------------------------------- prep
// Quantize to i8 scale 32 (clip 3.97 sigma): EA = Q(-x), EB = Q(x).
// sqnh = (sum Q(x)^2) >> 1 so screen acc = sqnh_j - S^2*xy directly.
__global__ __launch_bounds__(256) void prep_kernel(
    const float* __restrict__ E, int* __restrict__ sqnh,
    unsigned char* __restrict__ EA, unsigned char* __restrict__ EB,
    uint32* __restrict__ tauk) {
  const int row  = blockIdx.x * 4 + (threadIdx.x >> 6);
  const int lane = threadIdx.x & 63;
  const float4* e4 = (const float4*)(E + (size_t)row * DIM);
  const float4 f0 = e4[lane * 2];
  const float4 f1 = e4[lane * 2 + 1];
  const float xs[8] = {f0.x, f0.y, f0.z, f0.w, f1.x, f1.y, f1.z, f1.w};
  int ss = 0;
  uint32 pa0 = 0, pa1 = 0, pb0 = 0, pb1 = 0;
#pragma unroll
  for (int t = 0; t < 8; ++t) {
    const float v = fminf(fmaxf(xs[t] * 32.0f, -127.0f), 127.0f);
    const int q = __float2int_rn(v);
    ss += q * q;
    const uint32 ub = (uint32)(q & 0xFF);
    const uint32 ua = (uint32)((-q) & 0xFF);
    if (t < 4) { pb0 |= ub << (8 * t);       pa0 |= ua << (8 * t); }
    else       { pb1 |= ub << (8 * (t - 4)); pa1 |= ua << (8 * (t - 4)); }
  }
  uint2 wa; wa.x = pa0; wa.y = pa1;
  uint2 wb; wb.x = pb0; wb.y = pb1;
  ((uint2*)(EA + (size_t)row * DIM))[lane] = wa;
  ((uint2*)(EB + (size_t)row * DIM))[lane] = wb;
#pragma unroll
  for (int m = 32; m > 0; m >>= 1) ss += __shfl_xor(ss, m, 64);
  if (lane == 0) { sqnh[row] = ss >> 1; tauk[row] = EMPTYK; }
}

// ---------------------------------------------------------------- knn
// FUSED i8 screen. tau: device-global monotone bound via atomicMin,
// read fresh per subtile; published ONLY when it improves the global
// (kills ~90% of the 524k atomics that showed as 26MB of WRITE_SIZE).
__global__ __launch_bounds__(256, 4) void knn_kernel(
    const unsigned char* __restrict__ EA, const unsigned char* __restrict__ EB,
    const int* __restrict__ sqnh, uint32* __restrict__ tauk,
    uint32* __restrict__ knnk) {
  __shared__ __align__(16) char sm[KNN_LDS];
  uint32* sdp  = (uint32*)sm;
  int*    sqji = (int*)(sm + SQJ_OFF);

  const int tid = threadIdx.x;
  const int w   = tid >> 6;
  const int L   = tid & 63;
  const int wr  = (w >> 1) & 1;
  const int wc  = w & 1;
  const int i0  = blockIdx.x * NI;
  const int jsplit = blockIdx.y;
  const int j0  = jsplit * NJ;

  if (tid < NJ / 4) ((int4*)sqji)[tid] = ((const int4*)(sqnh + j0))[tid];

  const unsigned char* gsrc = (w < 2) ? EA : EB;
  const int lrow   = L >> 2;                               // 0..15
  const int swz_kB = ((L & 3) ^ ((L >> 3) & 3)) * 16;      // pre-swz, bytes
  const int lds_woff = ((w < 2) ? 0 : 8192) + (w & 1) * 4096;
  const int slotB  = (((L >> 4) ^ ((L >> 1) & 3)) * 16);   // same involution

  const int myrow = tid >> 1;
  const int h     = tid & 1;
  const int gi    = i0 + myrow;

  uint32 td[15];
#pragma unroll
  for (int p = 0; p < 15; ++p) td[p] = EMPTYK;

  __syncthreads();

  for (int js = 0; js < NSUB; ++js) {
    const int jrow0 = j0 + js * JS;
    const int trowW = ((w < 2) ? i0 : jrow0) + (w & 1) * 64;
    const unsigned char* gbase = gsrc + (size_t)(trowW + lrow) * DIM + swz_kB;

    // acc init = sqnh_j along the r (reg) dim
    i32x4 acc[4][4];
#pragma unroll
    for (int fj = 0; fj < 4; ++fj) {
      const i32x4 sq = *(const i32x4*)&sqji[js * 128 + wc * 64 + fj * 16 + (L >> 4) * 4];
#pragma unroll
      for (int fi = 0; fi < 4; ++fi) acc[fj][fi] = sq;
    }

    // prologue: stage chunk 0 into buf0 (4 x 16B per thread)
    {
      char* lp = sm + BUF0_OFF + lds_woff;
#pragma unroll
      for (int s = 0; s < 4; ++s)
        load_lds16(gbase + (size_t)(s * 16) * DIM, lp + s * 1024);
    }
    __syncthreads();

#pragma unroll 2
    for (int ch = 0; ch < NCH; ++ch) {
      const int cb  = (ch & 1) ? BUF1_OFF : BUF0_OFF;
      const int nbo = (ch & 1) ? BUF0_OFF : BUF1_OFF;
      if (ch < NCH - 1) {
        char* lp = sm + nbo + lds_woff;
        const unsigned char* gp = gbase + (ch + 1) * BKB;
#pragma unroll
        for (int s = 0; s < 4; ++s)
          load_lds16(gp + (size_t)(s * 16) * DIM, lp + s * 1024);
      }

      const char* sA = (const char*)(sm + cb);          // [128][64B]
      const char* sB = (const char*)(sm + cb + 8192);   // [128][64B]

      i32x4 a[4], b[4];
#pragma unroll
      for (int f = 0; f < 4; ++f) {
        a[f] = *(const i32x4*)&sA[(wr * 64 + f * 16 + (L & 15)) * BKB + slotB];
        b[f] = *(const i32x4*)&sB[(wc * 64 + f * 16 + (L & 15)) * BKB + slotB];
      }
      // swapped operands: reg dim = j (b), lane dim = i (a)
#pragma unroll
      for (int fj = 0; fj < 4; ++fj)
#pragma unroll
        for (int fi = 0; fi < 4; ++fi)
          acc[fj][fi] = __builtin_amdgcn_mfma_i32_16x16x64_i8(b[fj], a[fi], acc[fj][fi], 0, 0, 0);
      __syncthreads();   // drains next-chunk staging; orders buffer reuse
    }

    // ---- writeback: i32 -> f32 -> packed bf16, one b64 store per frag
#pragma unroll
    for (int fj = 0; fj < 4; ++fj)
#pragma unroll
      for (int fi = 0; fi < 4; ++fi) {
        const int i_t = wr * 64 + fi * 16 + (L & 15);
        const int jd  = wc * 32 + fj * 8 + (L >> 4) * 2;
        const float v0 = (float)acc[fj][fi][0];
        const float v1 = (float)acc[fj][fi][1];
        const float v2 = (float)acc[fj][fi][2];
        const float v3 = (float)acc[fj][fi][3];
        uint32 dw0, dw1;
        asm("v_cvt_pk_bf16_f32 %0, %1, %2" : "=v"(dw0) : "v"(v0), "v"(v1));
        asm("v_cvt_pk_bf16_f32 %0, %1, %2" : "=v"(dw1) : "v"(v2), "v"(v3));
        uint2 d2; d2.x = dw0; d2.y = dw1;
        *(uint2*)&sdp[i_t * SDW + jd] = d2;
      }
    __syncthreads();

    // fresh monotone tau (stale value = weaker guard, still correct)
    const uint32 tau_cur = __hip_atomic_load(&tauk[gi], __ATOMIC_RELAXED,
                                             __HIP_MEMORY_SCOPE_AGENT);
    const int selfc = gi - jrow0;
    if (selfc >= 0 && selfc < JS && h == (selfc >> 6))
      *(ushort*)(sm + myrow * (SDW * 4) + selfc * 2) = 0x7F80;   // bf16 +inf

    const uint32* rowp = sdp + myrow * SDW + 32 * h;
    const uint32 jb = (uint32)(jrow0 + 64 * h);
    uint32 guard = min(tau_cur, td[14]);
    uint32 nc = 0;
    uint32 p0=0,p1=0,p2=0,p3=0,p4=0,p5=0,p6=0,p7=0,p8=0,p9=0,p10=0,p11=0;

#pragma unroll 2
    for (int q = 0; q < 8; ++q) {
      const uint4 pv = *(const uint4*)&rowp[4 * q];
      const uint32 jq = jb + 8 * q;
      uint32 kx;
      kx = (pv.x << 16)          | (jq + 0); if (kx < guard) PUSHK(kx);
      kx = (pv.x & 0xFFFF0000u)  | (jq + 1); if (kx < guard) PUSHK(kx);
      kx = (pv.y << 16)          | (jq + 2); if (kx < guard) PUSHK(kx);
      kx = (pv.y & 0xFFFF0000u)  | (jq + 3); if (kx < guard) PUSHK(kx);
      kx = (pv.z << 16)          | (jq + 4); if (kx < guard) PUSHK(kx);
      kx = (pv.z & 0xFFFF0000u)  | (jq + 5); if (kx < guard) PUSHK(kx);
      kx = (pv.w << 16)          | (jq + 6); if (kx < guard) PUSHK(kx);
      kx = (pv.w & 0xFFFF0000u)  | (jq + 7); if (kx < guard) PUSHK(kx);
      if (__any(nc >= 4)) { DRAINALL; }
    }
    if (__any(nc > 0)) { DRAINALL; }

    // publish only when it improves the global bound (monotone, safe)
    if (td[14] < 0x7F000000u) {
      const uint32 cand = td[14] + TAU_MARGIN;
      if (cand < tau_cur) atomicMin(&tauk[gi], cand);
    }
    __syncthreads();
  }

  uint32* mdk = (uint32*)sm;
#pragma unroll
  for (int p = 0; p < 15; ++p) mdk[(myrow * 2 + h) * 15 + p] = td[p];
  __syncthreads();
  if (h == 0) {
    const uint32* la = &mdk[(myrow * 2 + 0) * 15];
    const uint32* lb = &mdk[(myrow * 2 + 1) * 15];
    int pa = 0, pb = 0;
    const size_t base = ((size_t)gi * NLIST + jsplit) * KNNK;
    for (int s = 0; s < KNNK; ++s) {
      const uint32 va = la[pa], vb = lb[pb];
      uint32 v;
      if (va <= vb) { v = va; ++pa; } else { v = vb; ++pb; }
      knnk[base + s] = v;
    }
  }
}

// ---------------------------------------------------------------- sig
// 240 keys (16 lists): radix-select rank-23 threshold (ballot+popc),
// ballot-prefix compaction (24 cands), parallel coalesced refine (3x8),
// rank sort, gram, bitonic-128.
__global__ __launch_bounds__(256) void sig_kernel(
    const float* __restrict__ E, const uint32* __restrict__ knnk,
    const float* __restrict__ refc, const float* __restrict__ refa,
    float2* __restrict__ pacc) {
  __shared__ float gsm[4][352];  // gram 0..271 | inv 272..287 | cand 288..311
                                 // dsel 312..326 | nbr 328..342

  const int tid = threadIdx.x;
  const int wid = tid >> 6;
  const int L   = tid & 63;
  const int i   = blockIdx.x * 4 + wid;

  const uint32* kl = knnk + (size_t)i * NKEYS;   // 240 keys
  const uint32 k0 = kl[L];
  const uint32 k1 = kl[L + 64];
  const uint32 k2 = kl[L + 128];
  const uint32 k3 = (L < NKEYS - 192) ? kl[L + 192] : EMPTYK;  // 192..239

  // ---- radix-select the rank-(NCAND-1) key T (max T with count(<T)<=23)
  uint32 T = 0;
  for (int b = 31; b >= 0; --b) {
    const uint32 Tt = T | (1u << b);
    const int cnt = __popcll(__ballot(k0 < Tt)) + __popcll(__ballot(k1 < Tt)) +
                    __popcll(__ballot(k2 < Tt)) + __popcll(__ballot(k3 < Tt));
    if (cnt <= NCAND - 1) T = Tt;
  }

  // ---- compact the exactly-NCAND keys <= T into LDS via ballot-prefix
  uint32* candL = (uint32*)&gsm[wid][288];
  {
    const unsigned long long B0 = __ballot(k0 <= T);
    const unsigned long long B1 = __ballot(k1 <= T);
    const unsigned long long B2 = __ballot(k2 <= T);
    const unsigned long long B3 = __ballot(k3 <= T);
    int off = 0;
    if (k0 <= T) candL[off + lanes_below(B0)] = k0;
    off += __popcll(B0);
    if (k1 <= T) candL[off + lanes_below(B1)] = k1;
    off += __popcll(B1);
    if (k2 <= T) candL[off + lanes_below(B2)] = k2;
    off += __popcll(B2);
    if (k3 <= T) candL[off + lanes_below(B3)] = k3;
  }
  asm volatile("s_waitcnt lgkmcnt(0)" ::: "memory");
  const uint32 cand_key = (L < NCAND) ? candL[L] : EMPTYK;
  int cand_nb = ((cand_key >> 16) < 0x7F80u) ? (int)(cand_key & 0x1FFFu) : i;

  // ---- parallel exact refine: round r covers candidates r*8+g,
  //      group g = L>>3; lane u = L&7 reads float4s u+8t (coalesced).
  const float* Ei = E + (size_t)i * DIM;
  const int u = L & 7;
  const int g = L >> 3;
  float sr[3];
#pragma unroll
  for (int r = 0; r < 3; ++r) {
    const int c = r * 8 + g;                    // 0..23
    const int row = __shfl(cand_nb, c, 64);
    const float4* r4 = (const float4*)(E + (size_t)row * DIM);
    const float4* e4 = (const float4*)Ei;
    float a0 = 0.f, a1 = 0.f, a2 = 0.f, a3 = 0.f;
#pragma unroll
    for (int t = 0; t < 16; ++t) {
      const float4 av = r4[u + 8 * t];
      const float4 ev = e4[u + 8 * t];
      const float d0 = av.x - ev.x, d1 = av.y - ev.y;
      const float d2 = av.z - ev.z, d3 = av.w - ev.w;
      a0 = fmaf(d0, d0, a0); a1 = fmaf(d1, d1, a1);
      a2 = fmaf(d2, d2, a2); a3 = fmaf(d3, d3, a3);
    }
    float s = (a0 + a1) + (a2 + a3);
    s += __shfl_xor(s, 1, 64);
    s += __shfl_xor(s, 2, 64);
    s += __shfl_xor(s, 4, 64);
    sr[r] = s;
  }
  const int srcl = (L & 7) * 8;
  const float t0 = __shfl(sr[0], srcl, 64);
  const float t1 = __shfl(sr[1], srcl, 64);
  const float t2 = __shfl(sr[2], srcl, 64);
  float csq = (L >> 3) == 0 ? t0 : ((L >> 3) == 1 ? t1 : t2);
  if (L >= NCAND || cand_nb == i) csq = CINF;

  // ---- rank sort: NCAND independent readlane compares -> LDS rank slot
  int rank = 0;
#pragma unroll
  for (int j = 0; j < NCAND; ++j) {
    const float vj = __shfl(csq, j, 64);
    rank += (vj < csq) || (vj == csq && j < L);
  }
  float* dselL = &gsm[wid][312];
  int*   nbrL  = (int*)&gsm[wid][328];
  if (L < NCAND && rank < KNNK) { dselL[rank] = csq; nbrL[rank] = cand_nb; }
  asm volatile("s_waitcnt lgkmcnt(0)" ::: "memory");
  const int sel = L & 15;
  const int mynb = (sel < KNNK) ? nbrL[sel] : i;
  const float myd = (L < KNNK) ? sqrtf(fmaxf(dselL[L], 1e-12f)) : 0.f;

  // ---- curvature (lanes 0..14 hold ranks 0..14)
  float curvs;
  {
    float dd = (L < KNNK) ? myd : 0.f;
    float tot = wave_sum_f(dd);
    float mean_d = tot / (float)KNNK + 1e-8f;
    float diff = (L < KNNK) ? (dd / mean_d - refc[i * KNNK + L]) : 0.f;
    curvs = wave_sum_f(diff * diff);
  }

  // ---- gram of raw neighbor differences (row = L&15; row 15 = self -> zero)
  const float4* nb4 = (const float4*)(E + (size_t)mynb * DIM);
  const float4* ei4 = (const float4*)Ei;
  const int qo = (L >> 4) * 2;

  typedef __attribute__((ext_vector_type(8))) short short8;
  typedef __attribute__((ext_vector_type(4))) float f32x4;
  f32x4 gH, gX1, gX2;
#pragma unroll
  for (int r = 0; r < 4; ++r) { gH[r] = 0.f; gX1[r] = 0.f; gX2[r] = 0.f; }

#pragma unroll
  for (int c = 0; c < 16; ++c) {
    const float4 f0 = nb4[qo + c * 8];
    const float4 f1 = nb4[qo + 1 + c * 8];
    const float4 g0 = ei4[qo + c * 8];
    const float4 g1 = ei4[qo + 1 + c * 8];
    float v[8];
    v[0] = f0.x - g0.x; v[1] = f0.y - g0.y; v[2] = f0.z - g0.z; v[3] = f0.w - g0.w;
    v[4] = f1.x - g1.x; v[5] = f1.y - g1.y; v[6] = f1.z - g1.z; v[7] = f1.w - g1.w;
    short8 ah, al;
#pragma unroll
    for (int q = 0; q < 8; ++q) {
      short hh, ll;
      bf16split(v[q], hh, ll);
      ah[q] = hh; al[q] = ll;
    }
    gH  = __builtin_amdgcn_mfma_f32_16x16x32_bf16(ah, ah, gH, 0, 0, 0);
    gX1 = __builtin_amdgcn_mfma_f32_16x16x32_bf16(ah, al, gX1, 0, 0, 0);
    gX2 = __builtin_amdgcn_mfma_f32_16x16x32_bf16(al, ah, gX2, 0, 0, 0);
  }

#pragma unroll
  for (int q = 0; q < 4; ++q)
    gsm[wid][((L >> 4) * 4 + q) * 17 + (L & 15)] = gH[q] + gX1[q] + gX2[q];
  asm volatile("s_waitcnt lgkmcnt(0)" ::: "memory");

  if (L < 16) {
    const float dv = gsm[wid][L * 17 + L];
    const float nrm = sqrtf(fmaxf(dv, 0.f));
    gsm[wid][272 + L] = 1.0f / fmaxf(nrm, 1e-8f);
  }
  asm volatile("s_waitcnt lgkmcnt(0)" ::: "memory");

  float c0 = CINF, c1 = CINF;
#pragma unroll
  for (int s = 0; s < 2; ++s) {
    const int p = L + 64 * s;
    if (p < NPAIR) {
      int a = 0, rem = p, cnt = 14;
      while (rem >= cnt) { rem -= cnt; --cnt; ++a; }
      const int b = a + 1 + rem;
      const float cv = gsm[wid][a * 17 + b] * gsm[wid][272 + a] * gsm[wid][272 + b];
      if (s == 0) c0 = cv; else c1 = cv;
    }
  }

  // bitonic-128 ascending
#pragma unroll
  for (int k = 2; k <= 128; k <<= 1) {
#pragma unroll
    for (int j = k >> 1; j >= 1; j >>= 1) {
      const bool dir = ((L & (k >> 1)) == 0);
      if (j == 1) {
        const float lo = fminf(c0, c1), hi = fmaxf(c0, c1);
        c0 = dir ? lo : hi;
        c1 = dir ? hi : lo;
      } else {
        const int m = j >> 1;
        const float o0 = __shfl_xor(c0, m, 64);
        const float o1 = __shfl_xor(c1, m, 64);
        const bool lower = ((L & m) == 0);
        c0 = (lower == dir) ? fminf(c0, o0) : fmaxf(c0, o0);
        c1 = (lower == dir) ? fminf(c1, o1) : fmaxf(c1, o1);
      }
    }
  }

  float part = 0.f;
  {
    const int r0 = 2 * L, r1 = 2 * L + 1;
    if (r0 < NPAIR) { const float dd = c0 - refa[(size_t)i * NPAIR + r0]; part += dd * dd; }
    if (r1 < NPAIR) { const float dd = c1 - refa[(size_t)i * NPAIR + r1]; part += dd * dd; }
  }
  part = wave_sum_f(part);
  if (L == 0) pacc[i] = make_float2(curvs, part);
}

// ---------------------------------------------------------------- fin
__global__ __launch_bounds__(256) void fin_kernel(
    const float2* __restrict__ pacc, float* __restrict__ out) {
  __shared__ double redc[4], reda[4];
  const int tid = threadIdx.x;
  const int wid = tid >> 6;
  const int L   = tid & 63;
  double sc = 0.0, sa = 0.0;
#pragma unroll
  for (int q = 0; q < 32; ++q) {
    const float2 p = pacc[tid + 256 * q];
    sc += (double)p.x;
    sa += (double)p.y;
  }
#pragma unroll
  for (int m = 32; m > 0; m >>= 1) {
    sc += __shfl_xor(sc, m, 64);
    sa += __shfl_xor(sa, m, 64);
  }
  if (L == 0) { redc[wid] = sc; reda[wid] = sa; }
  __syncthreads();
  if (tid == 0) {
    const double curv = (redc[0] + redc[1] + redc[2] + redc[3]) /
                        ((double)NPTS * (double)KNNK);
    const double ang  = (reda[0] + reda[1] + reda[2] + reda[3]) /
                        ((double)NPTS * (double)NPAIR);
    out[0] = (float)(0.3 * curv + 0.7 * ang);
  }
}

// ---------------------------------------------------------------- launch
extern "C" void kernel_launch(void* const* d_in, const int* in_sizes, int n_in,
                              void* d_out, int out_size, void* d_ws,
                              size_t ws_size, hipStream_t stream) {
  const float* E    = (const float*)d_in[0];
  const float* refc = (const float*)d_in[1];
  const float* refa = (const float*)d_in[2];
  float* out = (float*)d_out;

  char* ws = (char*)d_ws;
  int*    sqnh = (int*)(ws + 1024);
  float2* pacc = (float2*)(ws + 65536);
  uint32* tauk = (uint32*)(ws + 131072);      // [NPTS]
  unsigned char* EA = (unsigned char*)(ws + 1048576);   // 4 MB
  unsigned char* EB = (unsigned char*)(ws + 9437184);   // 4 MB
  uint32* knnk = (uint32*)(ws + 17825792);    // [NPTS][16][15] keys (7.9 MB)

  prep_kernel<<<NPTS / 4, 256, 0, stream>>>(E, sqnh, EA, EB, tauk);
  knn_kernel<<<dim3(NPTS / NI, NJSPLIT), 256, 0, stream>>>(EA, EB, sqnh, tauk, knnk);
  sig_kernel<<<NPTS / 4, 256, 0, stream>>>(E, knnk, refc, refa, pacc);
  fin_kernel<<<1, 256, 0, stream>>>(pacc, out);
}